// Round 1
// 494.853 us; speedup vs baseline: 1.0178x; 1.0178x over previous
//
#include <hip/hip_runtime.h>
#include <stdint.h>
#include <stddef.h>

#define T_SEQ 2048
#define WINDOW_SZ 1024

typedef __attribute__((ext_vector_type(4))) float f32x4;
typedef __attribute__((ext_vector_type(16))) float f32x16;
typedef __attribute__((ext_vector_type(8))) short s16x8;
typedef __attribute__((ext_vector_type(4))) short s16x4;

__device__ inline unsigned short f2bf(float f) {
  union { float f; unsigned u; } v; v.f = f;
  unsigned u = v.u;
  return (unsigned short)((u + 0x7fffu + ((u >> 16) & 1u)) >> 16);
}
__device__ inline float bf2f(unsigned short u) {
  union { unsigned u; float f; } v; v.u = ((unsigned)u) << 16; return v.f;
}

__device__ inline void gld_lds16(const unsigned short* g, unsigned short* l) {
  __builtin_amdgcn_global_load_lds((const __attribute__((address_space(1))) void*)g,
                                   (__attribute__((address_space(3))) void*)l, 16, 0, 0);
}

__device__ inline void store_out(float* p, float v) { *p = v; }
__device__ inline void store_out(unsigned short* p, float v) { *p = f2bf(v); }

// ---------------- fused fp32 -> bf16 convert for x, W_qkv, W_proj ----------------
__global__ __launch_bounds__(256) void cvt_all(const float* __restrict__ x,
                                               const float* __restrict__ wqkv,
                                               const float* __restrict__ wproj,
                                               unsigned short* __restrict__ x_bf,
                                               unsigned short* __restrict__ wqkv_bf,
                                               unsigned short* __restrict__ wproj_bf) {
  int i = blockIdx.x * 256 + threadIdx.x;  // 0 .. 12582912-1 float4s
  const float* s; unsigned short* d; int j;
  if (i < 2097152)       { s = x;     d = x_bf;     j = i; }
  else if (i < 8388608)  { s = wqkv;  d = wqkv_bf;  j = i - 2097152; }
  else                   { s = wproj; d = wproj_bf; j = i - 8388608; }
  float4 v = ((const float4*)s)[j];
  ushort4 o;
  o.x = f2bf(v.x); o.y = f2bf(v.y); o.z = f2bf(v.z); o.w = f2bf(v.w);
  ((ushort4*)d)[j] = o;
}

// ---------------- 128x128-tile bf16 GEMM (m97-class structure) — used for proj ----------------
template <typename OutT>
__global__ __launch_bounds__(256) void gemm_bt(const unsigned short* __restrict__ A,
                                               const unsigned short* __restrict__ Bt,
                                               OutT* __restrict__ C, int M, int N, int K) {
  __shared__ unsigned short As[128 * 64];  // row r chunk c at r*64+(c^(r&7))*8
  __shared__ unsigned short Bs[128 * 64];
  const int tid  = threadIdx.x;
  const int wave = tid >> 6, lane = tid & 63;
  const int l32 = lane & 31, khalf = lane >> 5;
  const int m0 = blockIdx.y << 7, n0 = blockIdx.x << 7;
  const int wr = (wave >> 1) << 6;
  const int wc = (wave & 1) << 6;
  const int srow = wave * 8 + (lane >> 3);
  const int gchunk0 = lane & 7;

  f32x16 acc[2][2] = {};

  for (int k0 = 0; k0 < K; k0 += 64) {
#pragma unroll
    for (int j = 0; j < 4; j++) {
      int r = j * 32 + srow;
      int gc = gchunk0 ^ (r & 7);
      gld_lds16(A  + (size_t)(m0 + r) * K + k0 + gc * 8, &As[(j * 32 + wave * 8) * 64]);
      gld_lds16(Bt + (size_t)(n0 + r) * K + k0 + gc * 8, &Bs[(j * 32 + wave * 8) * 64]);
    }
    __syncthreads();
#pragma unroll
    for (int s = 0; s < 4; s++) {
      s16x8 af[2], bfr[2];
      int chunk = s * 2 + khalf;
#pragma unroll
      for (int i = 0; i < 2; i++) {
        int ra = wr + i * 32 + l32;
        af[i]  = *(const s16x8*)&As[ra * 64 + ((chunk ^ (ra & 7)) * 8)];
        int rb = wc + i * 32 + l32;
        bfr[i] = *(const s16x8*)&Bs[rb * 64 + ((chunk ^ (rb & 7)) * 8)];
      }
#pragma unroll
      for (int mi = 0; mi < 2; mi++)
#pragma unroll
        for (int ni = 0; ni < 2; ni++)
          acc[mi][ni] = __builtin_amdgcn_mfma_f32_32x32x16_bf16(af[mi], bfr[ni], acc[mi][ni], 0, 0, 0);
    }
    __syncthreads();
  }
#pragma unroll
  for (int mi = 0; mi < 2; mi++)
#pragma unroll
    for (int ni = 0; ni < 2; ni++) {
      int col = n0 + wc + ni * 32 + l32;
      int rbase = m0 + wr + mi * 32 + 4 * khalf;
#pragma unroll
      for (int reg = 0; reg < 16; reg++) {
        int row = rbase + (reg & 3) + 8 * (reg >> 2);
        store_out(&C[(size_t)row * N + col], acc[mi][ni][reg]);
      }
    }
}

// ---------------- 256x256 8-wave phase-pipelined GEMM (T2+T3+T4+T5) — used for QKV ----------------
// C[M,N] = A[M,K] @ Bt[N,K]^T, bf16 in, bf16 out. BK=64, 4 phases per K-tile,
// counted vmcnt(4) once per tile (never drain to 0), raw barriers, setprio around MFMA.
// LDS 128 KiB: [buf][A 256x64 | B 256x64], chunk^(row&7) XOR swizzle (16B chunks).
// Staging order (provably race-free):
//   phase0: A(u+1) rows 0-127 -> buf^1  (last read of that region ended at tile u-1 phase3 barrier)
//   phase1: A(u+1) rows 128-255
//   phase2: B(u+2) rows 0-127 -> buf    (B of buf is only read at phase0 of tile u, done by phase1)
//   phase3: B(u+2) rows 128-255; then vmcnt(4) => {B(u+1),A(u+1)} landed, B(u+2) (4 loads) in flight.
__device__ inline void stage_half(const unsigned short* __restrict__ g, int ldk,
                                  int grow0, int k0, unsigned short* lds,
                                  int wave, int lane) {
#pragma unroll
  for (int j = 0; j < 2; j++) {
    int rloc = j * 64 + wave * 8 + (lane >> 3);
    int lc = (lane & 7) ^ (rloc & 7);   // pre-swizzled global source, linear LDS dest
    gld_lds16(g + (size_t)(grow0 + rloc) * ldk + k0 + lc * 8,
              lds + (j * 64 + wave * 8) * 64);
  }
}

__global__ __launch_bounds__(512, 2) void gemm256(const unsigned short* __restrict__ A,
                                                  const unsigned short* __restrict__ Bt,
                                                  unsigned short* __restrict__ C,
                                                  int M, int N, int K) {
  __shared__ unsigned short S[65536];   // 128 KiB: buf b: A at b*32768, B at b*32768+16384
  const int tid = threadIdx.x, wave = tid >> 6, lane = tid & 63;
  const int quad = lane >> 4, l16 = lane & 15;
  const int wm = wave >> 2, wn = wave & 3;          // 2 x 4 wave grid; wave owns 128x64 of C
  const int m0 = blockIdx.y << 8, n0 = blockIdx.x << 8;
  const int NT = K >> 6;

  f32x4 acc[8][4] = {};

  // prologue: B(0), A(0), B(1)  (12 loads/thread); wait until B(0)+A(0) landed (8 oldest)
  stage_half(Bt, K, n0,       0, &S[16384],        wave, lane);
  stage_half(Bt, K, n0 + 128, 0, &S[16384 + 8192], wave, lane);
  stage_half(A,  K, m0,       0, &S[0],            wave, lane);
  stage_half(A,  K, m0 + 128, 0, &S[8192],         wave, lane);
  if (NT > 1) {
    stage_half(Bt, K, n0,       64, &S[32768 + 16384],        wave, lane);
    stage_half(Bt, K, n0 + 128, 64, &S[32768 + 16384 + 8192], wave, lane);
  }
  asm volatile("s_waitcnt vmcnt(4)" ::: "memory");
  __builtin_amdgcn_s_barrier();
  asm volatile("" ::: "memory");

  for (int u = 0; u < NT; ++u) {
    const int b = u & 1;
    const unsigned short* Sa = &S[b * 32768];
    const unsigned short* Sb = &S[b * 32768 + 16384];
    s16x8 bfr[4][2];
#pragma unroll
    for (int p = 0; p < 4; ++p) {
      // --- ds-load register subtile (phase0: 12 reads, else 4) ---
      s16x8 af[2][2];
#pragma unroll
      for (int f = 0; f < 2; f++)
#pragma unroll
        for (int ks = 0; ks < 2; ks++) {
          int ra = wm * 128 + (p * 2 + f) * 16 + l16;
          af[f][ks] = *(const s16x8*)&Sa[ra * 64 + (((ks * 4 + quad) ^ (ra & 7)) * 8)];
        }
      if (p == 0) {
#pragma unroll
        for (int nf = 0; nf < 4; nf++)
#pragma unroll
          for (int ks = 0; ks < 2; ks++) {
            int rb = wn * 64 + nf * 16 + l16;
            bfr[nf][ks] = *(const s16x8*)&Sb[rb * 64 + (((ks * 4 + quad) ^ (rb & 7)) * 8)];
          }
      }
      // --- stage one half-tile ---
      if (p == 0 && u + 1 < NT) stage_half(A,  K, m0,       (u + 1) << 6, &S[(b ^ 1) * 32768],                wave, lane);
      if (p == 1 && u + 1 < NT) stage_half(A,  K, m0 + 128, (u + 1) << 6, &S[(b ^ 1) * 32768 + 8192],         wave, lane);
      if (p == 2 && u + 2 < NT) stage_half(Bt, K, n0,       (u + 2) << 6, &S[b * 32768 + 16384],              wave, lane);
      if (p == 3 && u + 2 < NT) stage_half(Bt, K, n0 + 128, (u + 2) << 6, &S[b * 32768 + 16384 + 8192],       wave, lane);

      asm volatile("" ::: "memory");
      __builtin_amdgcn_s_barrier();
      asm volatile("" ::: "memory");
      // --- 16 MFMA: C-quadrant (2 M-frags x 4 N-frags) x K=64 ---
      __builtin_amdgcn_s_setprio(1);
#pragma unroll
      for (int f = 0; f < 2; f++)
#pragma unroll
        for (int nf = 0; nf < 4; nf++)
#pragma unroll
          for (int ks = 0; ks < 2; ks++)
            acc[p * 2 + f][nf] = __builtin_amdgcn_mfma_f32_16x16x32_bf16(
                af[f][ks], bfr[nf][ks], acc[p * 2 + f][nf], 0, 0, 0);
      __builtin_amdgcn_s_setprio(0);
      if (p == 3) asm volatile("s_waitcnt vmcnt(4)" ::: "memory");
      asm volatile("" ::: "memory");
      __builtin_amdgcn_s_barrier();
      asm volatile("" ::: "memory");
    }
  }
  // C/D 16x16: col = lane&15, row = quad*4 + reg  [m89]
#pragma unroll
  for (int mf = 0; mf < 8; mf++)
#pragma unroll
    for (int nf = 0; nf < 4; nf++) {
      const int row0 = m0 + wm * 128 + mf * 16 + quad * 4;
      const int col  = n0 + wn * 64 + nf * 16 + l16;
#pragma unroll
      for (int r = 0; r < 4; r++)
        C[(size_t)(row0 + r) * N + col] = f2bf(acc[mf][nf][r]);
    }
}

// ---------------- fused RMSNorm + RoPE + layout (one block per token) ----------------
__global__ __launch_bounds__(256) void normrope(const unsigned short* __restrict__ qkv,
                                                const float* __restrict__ cosb,
                                                const float* __restrict__ sinb,
                                                const float* __restrict__ wq,
                                                const float* __restrict__ wk,
                                                unsigned short* __restrict__ qr,
                                                unsigned short* __restrict__ kr,
                                                unsigned short* __restrict__ vt) {
  const int t = blockIdx.x, tid = threadIdx.x;
  const unsigned short* row = qkv + (size_t)t * 6144;
  float sq = 0.f, sk = 0.f;
  {
    s16x8 a = *(const s16x8*)&row[tid * 16];
    s16x8 b = *(const s16x8*)&row[tid * 16 + 8];
#pragma unroll
    for (int j = 0; j < 8; j++) {
      float fa = bf2f((unsigned short)a[j]), fb = bf2f((unsigned short)b[j]);
      sq += fa * fa + fb * fb;
    }
  }
  {
    s16x4 a = *(const s16x4*)&row[4096 + tid * 4];
#pragma unroll
    for (int j = 0; j < 4; j++) {
      float fa = bf2f((unsigned short)a[j]);
      sk += fa * fa;
    }
  }
#pragma unroll
  for (int off = 32; off; off >>= 1) { sq += __shfl_xor(sq, off); sk += __shfl_xor(sk, off); }
  __shared__ float red[8];
  if ((tid & 63) == 0) { red[tid >> 6] = sq; red[4 + (tid >> 6)] = sk; }
  __syncthreads();
  sq = red[0] + red[1] + red[2] + red[3];
  sk = red[4] + red[5] + red[6] + red[7];
  const float rq = rsqrtf(sq * (1.f / 4096.f) + 1e-5f) * (0.08838834764831845f * 1.4426950408889634f);
  const float rk = rsqrtf(sk * (1.f / 1024.f) + 1e-5f);
  for (int i = tid; i < 4096; i += 256) {
    int h = i >> 7, d = i & 127;
    int pd = (d < 64) ? d + 64 : d - 64;
    float val = bf2f(row[i]) * rq * wq[i];
    float pv  = bf2f(row[(h << 7) + pd]) * rq * wq[(h << 7) + pd];
    float rot = (d < 64) ? -pv : pv;
    float o = val * cosb[t * 128 + d] + rot * sinb[t * 128 + d];
    qr[(size_t)h * T_SEQ * 128 + t * 128 + d] = f2bf(o);
  }
  for (int i = tid; i < 1024; i += 256) {
    int g = i >> 7, d = i & 127;
    int pd = (d < 64) ? d + 64 : d - 64;
    float val = bf2f(row[4096 + i]) * rk * wk[i];
    float pv  = bf2f(row[4096 + (g << 7) + pd]) * rk * wk[(g << 7) + pd];
    float rot = (d < 64) ? -pv : pv;
    float o = val * cosb[t * 128 + d] + rot * sinb[t * 128 + d];
    kr[(size_t)g * T_SEQ * 128 + t * 128 + d] = f2bf(o);
  }
  for (int i = tid; i < 1024; i += 256) {
    int g = i >> 7, d = i & 127;
    vt[(size_t)g * 128 * T_SEQ + (size_t)d * T_SEQ + t] = row[5120 + i];
  }
}

// ---------------- flash attention, sliding window, block-shared LDS K/V ----------------
__global__ __launch_bounds__(512, 2) void attn(const unsigned short* __restrict__ Q,
                                               const unsigned short* __restrict__ Kb,
                                               const unsigned short* __restrict__ Vt,
                                               unsigned short* __restrict__ Y) {
  __shared__ unsigned short Kbuf[2][64 * 128];
  __shared__ unsigned short Vbuf[2][128 * 64];
  __shared__ unsigned short Pbuf[8][2][16 * 72];
  const int qb = blockIdx.x, g = blockIdx.y;
  const int tid = threadIdx.x, wave = tid >> 6, lane = tid & 63;
  const int quad = lane >> 4, l16 = lane & 15;
  const int h = g * 4 + (wave >> 1);
  const int qbase = qb * 64;
  const int q0 = qbase + (wave & 1) * 32;
  const unsigned short* Qh = Q + (size_t)h * T_SEQ * 128;
  const unsigned short* Kg = Kb + (size_t)g * T_SEQ * 128;
  const unsigned short* Vg = Vt + (size_t)g * 128 * T_SEQ;

  s16x8 aq[2][4];
#pragma unroll
  for (int qt = 0; qt < 2; qt++)
#pragma unroll
    for (int ks = 0; ks < 4; ks++)
      aq[qt][ks] = *(const s16x8*)&Qh[(size_t)(q0 + qt * 16 + l16) * 128 + ks * 32 + quad * 8];

  f32x4 acc[2][8] = {};
  float lrow[2][4] = {};

  int lo = qbase - (WINDOW_SZ - 1);
  if (lo < 0) lo = 0;
  lo &= ~63;

#define STAGE_CHUNK(buf, kkv)                                                        \
  {                                                                                  \
    int kk_ = (kkv);                                                                 \
    _Pragma("unroll")                                                                \
    for (int j = 0; j < 2; j++) {                                                    \
      int rloc = wave * 8 + j * 4 + (lane >> 4);                                     \
      int oct = (lane & 15) ^ (rloc & 15);                                           \
      gld_lds16(Kg + (size_t)(kk_ + rloc) * 128 + oct * 8,                           \
                &Kbuf[buf][(wave * 8 + j * 4) * 128]);                               \
    }                                                                                \
    _Pragma("unroll")                                                                \
    for (int j = 0; j < 2; j++) {                                                    \
      int dloc = wave * 16 + j * 8 + (lane >> 3);                                    \
      int oct = (lane & 7) ^ (dloc & 7);                                             \
      gld_lds16(Vg + (size_t)dloc * T_SEQ + kk_ + oct * 8,                           \
                &Vbuf[buf][(wave * 16 + j * 8) * 64]);                               \
    }                                                                                \
  }

  STAGE_CHUNK(0, lo);
  int ib = 0;
  for (int kk = lo; kk < qbase + 64; kk += 64, ib ^= 1) {
    __syncthreads();
    if (kk + 64 < qbase + 64) STAGE_CHUNK(ib ^ 1, kk + 64);
    if (kk > q0 + 31 || kk + 63 < q0 - (WINDOW_SZ - 1)) continue;
    const unsigned short* kb = Kbuf[ib];
    const unsigned short* vb = Vbuf[ib];
    f32x4 sc[2][4] = {};
    __builtin_amdgcn_s_setprio(1);
#pragma unroll
    for (int ks = 0; ks < 4; ks++) {
#pragma unroll
      for (int ci = 0; ci < 4; ci++) {
        s16x8 bk = *(const s16x8*)&kb[(ci * 16 + l16) * 128 + (((ks * 4 + quad) ^ l16) * 8)];
        sc[0][ci] = __builtin_amdgcn_mfma_f32_16x16x32_bf16(aq[0][ks], bk, sc[0][ci], 0, 0, 0);
        sc[1][ci] = __builtin_amdgcn_mfma_f32_16x16x32_bf16(aq[1][ks], bk, sc[1][ci], 0, 0, 0);
      }
    }
    __builtin_amdgcn_s_setprio(0);
#pragma unroll
    for (int qt = 0; qt < 2; qt++)
#pragma unroll
      for (int ci = 0; ci < 4; ci++) {
        int col = kk + ci * 16 + l16;
#pragma unroll
        for (int r = 0; r < 4; r++) {
          int irow = q0 + qt * 16 + quad * 4 + r;
          unsigned dd = (unsigned)(irow - col);
          float e = (dd < (unsigned)WINDOW_SZ) ? exp2f(sc[qt][ci][r]) : 0.f;
          lrow[qt][r] += e;
          Pbuf[wave][qt][(quad * 4 + r) * 72 + ci * 16 + l16] = f2bf(e);
        }
      }
    __builtin_amdgcn_s_setprio(1);
#pragma unroll
    for (int c = 0; c < 2; c++) {
      s16x8 pa0 = *(const s16x8*)&Pbuf[wave][0][l16 * 72 + c * 32 + quad * 8];
      s16x8 pa1 = *(const s16x8*)&Pbuf[wave][1][l16 * 72 + c * 32 + quad * 8];
#pragma unroll
      for (int n = 0; n < 8; n++) {
        s16x8 bv = *(const s16x8*)&vb[(n * 16 + l16) * 64 + (((c * 4 + quad) ^ (l16 & 7)) * 8)];
        acc[0][n] = __builtin_amdgcn_mfma_f32_16x16x32_bf16(pa0, bv, acc[0][n], 0, 0, 0);
        acc[1][n] = __builtin_amdgcn_mfma_f32_16x16x32_bf16(pa1, bv, acc[1][n], 0, 0, 0);
      }
    }
    __builtin_amdgcn_s_setprio(0);
  }
#undef STAGE_CHUNK
#pragma unroll
  for (int qt = 0; qt < 2; qt++)
#pragma unroll
    for (int r = 0; r < 4; r++) {
#pragma unroll
      for (int off = 8; off; off >>= 1) lrow[qt][r] += __shfl_xor(lrow[qt][r], off);
      lrow[qt][r] = 1.f / lrow[qt][r];
    }
#pragma unroll
  for (int qt = 0; qt < 2; qt++)
#pragma unroll
    for (int n = 0; n < 8; n++)
#pragma unroll
      for (int r = 0; r < 4; r++) {
        int irow = q0 + qt * 16 + quad * 4 + r;
        Y[(size_t)irow * 4096 + h * 128 + n * 16 + l16] = f2bf(acc[qt][n][r] * lrow[qt][r]);
      }
}

extern "C" void kernel_launch(void* const* d_in, const int* in_sizes, int n_in,
                              void* d_out, int out_size, void* d_ws, size_t ws_size,
                              hipStream_t stream) {
  (void)in_sizes; (void)n_in; (void)out_size; (void)ws_size;
  const float* x     = (const float*)d_in[0];
  const float* cosb  = (const float*)d_in[1];
  const float* sinb  = (const float*)d_in[2];
  const float* Wqkv  = (const float*)d_in[3];
  const float* wq    = (const float*)d_in[4];
  const float* wk    = (const float*)d_in[5];
  const float* Wproj = (const float*)d_in[6];
  float* out = (float*)d_out;

  char* ws = (char*)d_ws;
  unsigned short* x_bf     = (unsigned short*)(ws);                 // 16 MB
  unsigned short* wqkv_bf  = (unsigned short*)(ws + 16777216);      // 48 MB
  unsigned short* wproj_bf = (unsigned short*)(ws + 67108864);      // 32 MB
  unsigned short* qkv      = (unsigned short*)(ws + 100663296);     // 24 MB (bf16)
  unsigned short* qr       = (unsigned short*)(ws + 150994944);     // 16 MB
  unsigned short* kr       = (unsigned short*)(ws + 167772160);     // 4 MB
  unsigned short* vt       = (unsigned short*)(ws + 171966464);     // 4 MB
  unsigned short* y        = (unsigned short*)(ws + 176160768);     // 16 MB

  cvt_all<<<49152, 256, 0, stream>>>(x, Wqkv, Wproj, x_bf, wqkv_bf, wproj_bf);
  gemm256<<<dim3(24, 8), 512, 0, stream>>>(x_bf, wqkv_bf, qkv, 2048, 6144, 4096);
  normrope<<<2048, 256, 0, stream>>>(qkv, cosb, sinb, wq, wk, qr, kr, vt);
  attn<<<dim3(32, 8), 512, 0, stream>>>(qr, kr, vt, y);
  gemm_bt<float><<<dim3(32, 16), 256, 0, stream>>>(y, wproj_bf, out, 2048, 4096, 4096);
}

// Round 2
// 479.990 us; speedup vs baseline: 1.0493x; 1.0310x over previous
//
#include <hip/hip_runtime.h>
#include <stdint.h>
#include <stddef.h>

#define T_SEQ 2048
#define WINDOW_SZ 1024

typedef __attribute__((ext_vector_type(4))) float f32x4;
typedef __attribute__((ext_vector_type(16))) float f32x16;
typedef __attribute__((ext_vector_type(8))) short s16x8;
typedef __attribute__((ext_vector_type(4))) short s16x4;

__device__ inline unsigned short f2bf(float f) {
  union { float f; unsigned u; } v; v.f = f;
  unsigned u = v.u;
  return (unsigned short)((u + 0x7fffu + ((u >> 16) & 1u)) >> 16);
}
__device__ inline float bf2f(unsigned short u) {
  union { unsigned u; float f; } v; v.u = ((unsigned)u) << 16; return v.f;
}

__device__ inline void gld_lds16(const unsigned short* g, unsigned short* l) {
  __builtin_amdgcn_global_load_lds((const __attribute__((address_space(1))) void*)g,
                                   (__attribute__((address_space(3))) void*)l, 16, 0, 0);
}

__device__ inline void store_out(float* p, float v) { *p = v; }
__device__ inline void store_out(unsigned short* p, float v) { *p = f2bf(v); }

// ---------------- fused fp32 -> bf16 convert for x, W_qkv, W_proj ----------------
__global__ __launch_bounds__(256) void cvt_all(const float* __restrict__ x,
                                               const float* __restrict__ wqkv,
                                               const float* __restrict__ wproj,
                                               unsigned short* __restrict__ x_bf,
                                               unsigned short* __restrict__ wqkv_bf,
                                               unsigned short* __restrict__ wproj_bf) {
  int i = blockIdx.x * 256 + threadIdx.x;  // 0 .. 12582912-1 float4s
  const float* s; unsigned short* d; int j;
  if (i < 2097152)       { s = x;     d = x_bf;     j = i; }
  else if (i < 8388608)  { s = wqkv;  d = wqkv_bf;  j = i - 2097152; }
  else                   { s = wproj; d = wproj_bf; j = i - 8388608; }
  float4 v = ((const float4*)s)[j];
  ushort4 o;
  o.x = f2bf(v.x); o.y = f2bf(v.y); o.z = f2bf(v.z); o.w = f2bf(v.w);
  ((ushort4*)d)[j] = o;
}

// ---------------- 128x128-tile bf16 GEMM (m97-class structure) — used for proj ----------------
template <typename OutT>
__global__ __launch_bounds__(256) void gemm_bt(const unsigned short* __restrict__ A,
                                               const unsigned short* __restrict__ Bt,
                                               OutT* __restrict__ C, int M, int N, int K) {
  __shared__ unsigned short As[128 * 64];  // row r chunk c at r*64+(c^(r&7))*8
  __shared__ unsigned short Bs[128 * 64];
  const int tid  = threadIdx.x;
  const int wave = tid >> 6, lane = tid & 63;
  const int l32 = lane & 31, khalf = lane >> 5;
  const int m0 = blockIdx.y << 7, n0 = blockIdx.x << 7;
  const int wr = (wave >> 1) << 6;
  const int wc = (wave & 1) << 6;
  const int srow = wave * 8 + (lane >> 3);
  const int gchunk0 = lane & 7;

  f32x16 acc[2][2] = {};

  for (int k0 = 0; k0 < K; k0 += 64) {
#pragma unroll
    for (int j = 0; j < 4; j++) {
      int r = j * 32 + srow;
      int gc = gchunk0 ^ (r & 7);
      gld_lds16(A  + (size_t)(m0 + r) * K + k0 + gc * 8, &As[(j * 32 + wave * 8) * 64]);
      gld_lds16(Bt + (size_t)(n0 + r) * K + k0 + gc * 8, &Bs[(j * 32 + wave * 8) * 64]);
    }
    __syncthreads();
#pragma unroll
    for (int s = 0; s < 4; s++) {
      s16x8 af[2], bfr[2];
      int chunk = s * 2 + khalf;
#pragma unroll
      for (int i = 0; i < 2; i++) {
        int ra = wr + i * 32 + l32;
        af[i]  = *(const s16x8*)&As[ra * 64 + ((chunk ^ (ra & 7)) * 8)];
        int rb = wc + i * 32 + l32;
        bfr[i] = *(const s16x8*)&Bs[rb * 64 + ((chunk ^ (rb & 7)) * 8)];
      }
#pragma unroll
      for (int mi = 0; mi < 2; mi++)
#pragma unroll
        for (int ni = 0; ni < 2; ni++)
          acc[mi][ni] = __builtin_amdgcn_mfma_f32_32x32x16_bf16(af[mi], bfr[ni], acc[mi][ni], 0, 0, 0);
    }
    __syncthreads();
  }
#pragma unroll
  for (int mi = 0; mi < 2; mi++)
#pragma unroll
    for (int ni = 0; ni < 2; ni++) {
      int col = n0 + wc + ni * 32 + l32;
      int rbase = m0 + wr + mi * 32 + 4 * khalf;
#pragma unroll
      for (int reg = 0; reg < 16; reg++) {
        int row = rbase + (reg & 3) + 8 * (reg >> 2);
        store_out(&C[(size_t)row * N + col], acc[mi][ni][reg]);
      }
    }
}

// ---------------- 256x192 8-wave phase-pipelined GEMM (T2+T3+T4+T5) — used for QKV ----------------
// BM=256, BN=192, BK=64 -> grid (N/192, M/256) = (32,8) = 256 blocks, exactly 1/CU, 0 idle CUs.
// Same verified schedule as R1 (counted vmcnt, never drained mid-loop; raw barriers; setprio):
//   phase0: read af(q0)+all bfr; stage A(u+1) rows 0-127   -> buf^1
//   phase1: read af(q1);         stage A(u+1) rows 128-255 -> buf^1
//   phase2: read af(q2);         stage B(u+2) rows 0-127   -> buf (B region free after p0 reads)
//   phase3: read af(q3);         stage B(u+2) rows 128-191 (1 load); vmcnt(3) -> {B(u+1),A(u+1)}
//           landed, B(u+2)'s 3 loads stay in flight. Tail (u+2>=NT): vmcnt(0) — also fixes the
//           R1 latent race where A(NT-1) wasn't covered by vmcnt(4) once staging stopped.
__device__ inline void stage_half(const unsigned short* __restrict__ g, int ldk,
                                  int grow0, int k0, unsigned short* lds,
                                  int wave, int lane) {
#pragma unroll
  for (int j = 0; j < 2; j++) {
    int rloc = j * 64 + wave * 8 + (lane >> 3);
    int lc = (lane & 7) ^ (rloc & 7);   // pre-swizzled global source, linear LDS dest
    gld_lds16(g + (size_t)(grow0 + rloc) * ldk + k0 + lc * 8,
              lds + (j * 64 + wave * 8) * 64);
  }
}
__device__ inline void stage_64(const unsigned short* __restrict__ g, int ldk,
                                int grow0, int k0, unsigned short* lds,
                                int wave, int lane) {
  int rloc = wave * 8 + (lane >> 3);
  int lc = (lane & 7) ^ (rloc & 7);
  gld_lds16(g + (size_t)(grow0 + rloc) * ldk + k0 + lc * 8,
            lds + (wave * 8) * 64);
}

__global__ __launch_bounds__(512, 2) void gemm256(const unsigned short* __restrict__ A,
                                                  const unsigned short* __restrict__ Bt,
                                                  unsigned short* __restrict__ C,
                                                  int M, int N, int K) {
  // LDS 112 KiB: buf b: A (256x64, 16384 elems) at b*28672, B (192x64, 12288 elems) at +16384
  __shared__ unsigned short S[57344];
  const int tid = threadIdx.x, wave = tid >> 6, lane = tid & 63;
  const int quad = lane >> 4, l16 = lane & 15;
  const int wm = wave >> 2, wn = wave & 3;          // 2 x 4 wave grid; wave owns 128x48 of C
  const int m0 = blockIdx.y << 8, n0 = blockIdx.x * 192;
  const int NT = K >> 6;

  f32x4 acc[8][3] = {};

  // prologue: B(0) (3 loads), A(0) (4), B(1) (3); wait until B(0)+A(0) landed (7 oldest)
  stage_half(Bt, K, n0,       0, &S[16384],        wave, lane);
  stage_64  (Bt, K, n0 + 128, 0, &S[16384 + 8192], wave, lane);
  stage_half(A,  K, m0,       0, &S[0],            wave, lane);
  stage_half(A,  K, m0 + 128, 0, &S[8192],         wave, lane);
  if (NT > 1) {
    stage_half(Bt, K, n0,       64, &S[28672 + 16384],        wave, lane);
    stage_64  (Bt, K, n0 + 128, 64, &S[28672 + 16384 + 8192], wave, lane);
  }
  asm volatile("s_waitcnt vmcnt(3)" ::: "memory");
  __builtin_amdgcn_s_barrier();
  asm volatile("" ::: "memory");

  for (int u = 0; u < NT; ++u) {
    const int b = u & 1;
    const unsigned short* Sa = &S[b * 28672];
    const unsigned short* Sb = &S[b * 28672 + 16384];
    s16x8 bfr[3][2];
#pragma unroll
    for (int p = 0; p < 4; ++p) {
      // --- ds-load register subtile (phase0: 10 reads, else 4) ---
      s16x8 af[2][2];
#pragma unroll
      for (int f = 0; f < 2; f++)
#pragma unroll
        for (int ks = 0; ks < 2; ks++) {
          int ra = wm * 128 + (p * 2 + f) * 16 + l16;
          af[f][ks] = *(const s16x8*)&Sa[ra * 64 + (((ks * 4 + quad) ^ (ra & 7)) * 8)];
        }
      if (p == 0) {
#pragma unroll
        for (int nf = 0; nf < 3; nf++)
#pragma unroll
          for (int ks = 0; ks < 2; ks++) {
            int rb = wn * 48 + nf * 16 + l16;
            bfr[nf][ks] = *(const s16x8*)&Sb[rb * 64 + (((ks * 4 + quad) ^ (rb & 7)) * 8)];
          }
      }
      // --- stage one half-tile ---
      if (p == 0 && u + 1 < NT) stage_half(A,  K, m0,       (u + 1) << 6, &S[(b ^ 1) * 28672],        wave, lane);
      if (p == 1 && u + 1 < NT) stage_half(A,  K, m0 + 128, (u + 1) << 6, &S[(b ^ 1) * 28672 + 8192], wave, lane);
      if (p == 2 && u + 2 < NT) stage_half(Bt, K, n0,       (u + 2) << 6, &S[b * 28672 + 16384],      wave, lane);
      if (p == 3 && u + 2 < NT) stage_64  (Bt, K, n0 + 128, (u + 2) << 6, &S[b * 28672 + 24576],      wave, lane);

      asm volatile("" ::: "memory");
      __builtin_amdgcn_s_barrier();
      asm volatile("" ::: "memory");
      // --- 12 MFMA: C-quadrant (2 M-frags x 3 N-frags) x K=64 ---
      __builtin_amdgcn_s_setprio(1);
#pragma unroll
      for (int f = 0; f < 2; f++)
#pragma unroll
        for (int nf = 0; nf < 3; nf++)
#pragma unroll
          for (int ks = 0; ks < 2; ks++)
            acc[p * 2 + f][nf] = __builtin_amdgcn_mfma_f32_16x16x32_bf16(
                af[f][ks], bfr[nf][ks], acc[p * 2 + f][nf], 0, 0, 0);
      __builtin_amdgcn_s_setprio(0);
      if (p == 3) {
        if (u + 2 < NT) asm volatile("s_waitcnt vmcnt(3)" ::: "memory");
        else            asm volatile("s_waitcnt vmcnt(0)" ::: "memory");
      }
      asm volatile("" ::: "memory");
      __builtin_amdgcn_s_barrier();
      asm volatile("" ::: "memory");
    }
  }
  // C/D 16x16: col = lane&15, row = quad*4 + reg  [m89]
#pragma unroll
  for (int mf = 0; mf < 8; mf++)
#pragma unroll
    for (int nf = 0; nf < 3; nf++) {
      const int row0 = m0 + wm * 128 + mf * 16 + quad * 4;
      const int col  = n0 + wn * 48 + nf * 16 + l16;
#pragma unroll
      for (int r = 0; r < 4; r++)
        C[(size_t)(row0 + r) * N + col] = f2bf(acc[mf][nf][r]);
    }
}

// ---------------- fused RMSNorm + RoPE + layout (one block per token) ----------------
__global__ __launch_bounds__(256) void normrope(const unsigned short* __restrict__ qkv,
                                                const float* __restrict__ cosb,
                                                const float* __restrict__ sinb,
                                                const float* __restrict__ wq,
                                                const float* __restrict__ wk,
                                                unsigned short* __restrict__ qr,
                                                unsigned short* __restrict__ kr,
                                                unsigned short* __restrict__ vt) {
  const int t = blockIdx.x, tid = threadIdx.x;
  const unsigned short* row = qkv + (size_t)t * 6144;
  float sq = 0.f, sk = 0.f;
  {
    s16x8 a = *(const s16x8*)&row[tid * 16];
    s16x8 b = *(const s16x8*)&row[tid * 16 + 8];
#pragma unroll
    for (int j = 0; j < 8; j++) {
      float fa = bf2f((unsigned short)a[j]), fb = bf2f((unsigned short)b[j]);
      sq += fa * fa + fb * fb;
    }
  }
  {
    s16x4 a = *(const s16x4*)&row[4096 + tid * 4];
#pragma unroll
    for (int j = 0; j < 4; j++) {
      float fa = bf2f((unsigned short)a[j]);
      sk += fa * fa;
    }
  }
#pragma unroll
  for (int off = 32; off; off >>= 1) { sq += __shfl_xor(sq, off); sk += __shfl_xor(sk, off); }
  __shared__ float red[8];
  if ((tid & 63) == 0) { red[tid >> 6] = sq; red[4 + (tid >> 6)] = sk; }
  __syncthreads();
  sq = red[0] + red[1] + red[2] + red[3];
  sk = red[4] + red[5] + red[6] + red[7];
  const float rq = rsqrtf(sq * (1.f / 4096.f) + 1e-5f) * (0.08838834764831845f * 1.4426950408889634f);
  const float rk = rsqrtf(sk * (1.f / 1024.f) + 1e-5f);
  for (int i = tid; i < 4096; i += 256) {
    int h = i >> 7, d = i & 127;
    int pd = (d < 64) ? d + 64 : d - 64;
    float val = bf2f(row[i]) * rq * wq[i];
    float pv  = bf2f(row[(h << 7) + pd]) * rq * wq[(h << 7) + pd];
    float rot = (d < 64) ? -pv : pv;
    float o = val * cosb[t * 128 + d] + rot * sinb[t * 128 + d];
    qr[(size_t)h * T_SEQ * 128 + t * 128 + d] = f2bf(o);
  }
  for (int i = tid; i < 1024; i += 256) {
    int g = i >> 7, d = i & 127;
    int pd = (d < 64) ? d + 64 : d - 64;
    float val = bf2f(row[4096 + i]) * rk * wk[i];
    float pv  = bf2f(row[4096 + (g << 7) + pd]) * rk * wk[(g << 7) + pd];
    float rot = (d < 64) ? -pv : pv;
    float o = val * cosb[t * 128 + d] + rot * sinb[t * 128 + d];
    kr[(size_t)g * T_SEQ * 128 + t * 128 + d] = f2bf(o);
  }
  for (int i = tid; i < 1024; i += 256) {
    int g = i >> 7, d = i & 127;
    vt[(size_t)g * 128 * T_SEQ + (size_t)d * T_SEQ + t] = row[5120 + i];
  }
}

// ---------------- flash attention, sliding window, block-shared LDS K/V ----------------
__global__ __launch_bounds__(512, 2) void attn(const unsigned short* __restrict__ Q,
                                               const unsigned short* __restrict__ Kb,
                                               const unsigned short* __restrict__ Vt,
                                               unsigned short* __restrict__ Y) {
  __shared__ unsigned short Kbuf[2][64 * 128];
  __shared__ unsigned short Vbuf[2][128 * 64];
  __shared__ unsigned short Pbuf[8][2][16 * 72];
  const int qb = blockIdx.x, g = blockIdx.y;
  const int tid = threadIdx.x, wave = tid >> 6, lane = tid & 63;
  const int quad = lane >> 4, l16 = lane & 15;
  const int h = g * 4 + (wave >> 1);
  const int qbase = qb * 64;
  const int q0 = qbase + (wave & 1) * 32;
  const unsigned short* Qh = Q + (size_t)h * T_SEQ * 128;
  const unsigned short* Kg = Kb + (size_t)g * T_SEQ * 128;
  const unsigned short* Vg = Vt + (size_t)g * 128 * T_SEQ;

  s16x8 aq[2][4];
#pragma unroll
  for (int qt = 0; qt < 2; qt++)
#pragma unroll
    for (int ks = 0; ks < 4; ks++)
      aq[qt][ks] = *(const s16x8*)&Qh[(size_t)(q0 + qt * 16 + l16) * 128 + ks * 32 + quad * 8];

  f32x4 acc[2][8] = {};
  float lrow[2][4] = {};

  int lo = qbase - (WINDOW_SZ - 1);
  if (lo < 0) lo = 0;
  lo &= ~63;

#define STAGE_CHUNK(buf, kkv)                                                        \
  {                                                                                  \
    int kk_ = (kkv);                                                                 \
    _Pragma("unroll")                                                                \
    for (int j = 0; j < 2; j++) {                                                    \
      int rloc = wave * 8 + j * 4 + (lane >> 4);                                     \
      int oct = (lane & 15) ^ (rloc & 15);                                           \
      gld_lds16(Kg + (size_t)(kk_ + rloc) * 128 + oct * 8,                           \
                &Kbuf[buf][(wave * 8 + j * 4) * 128]);                               \
    }                                                                                \
    _Pragma("unroll")                                                                \
    for (int j = 0; j < 2; j++) {                                                    \
      int dloc = wave * 16 + j * 8 + (lane >> 3);                                    \
      int oct = (lane & 7) ^ (dloc & 7);                                             \
      gld_lds16(Vg + (size_t)dloc * T_SEQ + kk_ + oct * 8,                           \
                &Vbuf[buf][(wave * 16 + j * 8) * 64]);                               \
    }                                                                                \
  }

  STAGE_CHUNK(0, lo);
  int ib = 0;
  for (int kk = lo; kk < qbase + 64; kk += 64, ib ^= 1) {
    __syncthreads();
    if (kk + 64 < qbase + 64) STAGE_CHUNK(ib ^ 1, kk + 64);
    if (kk > q0 + 31 || kk + 63 < q0 - (WINDOW_SZ - 1)) continue;
    const unsigned short* kb = Kbuf[ib];
    const unsigned short* vb = Vbuf[ib];
    f32x4 sc[2][4] = {};
    __builtin_amdgcn_s_setprio(1);
#pragma unroll
    for (int ks = 0; ks < 4; ks++) {
#pragma unroll
      for (int ci = 0; ci < 4; ci++) {
        s16x8 bk = *(const s16x8*)&kb[(ci * 16 + l16) * 128 + (((ks * 4 + quad) ^ l16) * 8)];
        sc[0][ci] = __builtin_amdgcn_mfma_f32_16x16x32_bf16(aq[0][ks], bk, sc[0][ci], 0, 0, 0);
        sc[1][ci] = __builtin_amdgcn_mfma_f32_16x16x32_bf16(aq[1][ks], bk, sc[1][ci], 0, 0, 0);
      }
    }
    __builtin_amdgcn_s_setprio(0);
#pragma unroll
    for (int qt = 0; qt < 2; qt++)
#pragma unroll
      for (int ci = 0; ci < 4; ci++) {
        int col = kk + ci * 16 + l16;
#pragma unroll
        for (int r = 0; r < 4; r++) {
          int irow = q0 + qt * 16 + quad * 4 + r;
          unsigned dd = (unsigned)(irow - col);
          float e = (dd < (unsigned)WINDOW_SZ) ? exp2f(sc[qt][ci][r]) : 0.f;
          lrow[qt][r] += e;
          Pbuf[wave][qt][(quad * 4 + r) * 72 + ci * 16 + l16] = f2bf(e);
        }
      }
    __builtin_amdgcn_s_setprio(1);
#pragma unroll
    for (int c = 0; c < 2; c++) {
      s16x8 pa0 = *(const s16x8*)&Pbuf[wave][0][l16 * 72 + c * 32 + quad * 8];
      s16x8 pa1 = *(const s16x8*)&Pbuf[wave][1][l16 * 72 + c * 32 + quad * 8];
#pragma unroll
      for (int n = 0; n < 8; n++) {
        s16x8 bv = *(const s16x8*)&vb[(n * 16 + l16) * 64 + (((c * 4 + quad) ^ (l16 & 7)) * 8)];
        acc[0][n] = __builtin_amdgcn_mfma_f32_16x16x32_bf16(pa0, bv, acc[0][n], 0, 0, 0);
        acc[1][n] = __builtin_amdgcn_mfma_f32_16x16x32_bf16(pa1, bv, acc[1][n], 0, 0, 0);
      }
    }
    __builtin_amdgcn_s_setprio(0);
  }
#undef STAGE_CHUNK
#pragma unroll
  for (int qt = 0; qt < 2; qt++)
#pragma unroll
    for (int r = 0; r < 4; r++) {
#pragma unroll
      for (int off = 8; off; off >>= 1) lrow[qt][r] += __shfl_xor(lrow[qt][r], off);
      lrow[qt][r] = 1.f / lrow[qt][r];
    }
#pragma unroll
  for (int qt = 0; qt < 2; qt++)
#pragma unroll
    for (int n = 0; n < 8; n++)
#pragma unroll
      for (int r = 0; r < 4; r++) {
        int irow = q0 + qt * 16 + quad * 4 + r;
        Y[(size_t)irow * 4096 + h * 128 + n * 16 + l16] = f2bf(acc[qt][n][r] * lrow[qt][r]);
      }
}

extern "C" void kernel_launch(void* const* d_in, const int* in_sizes, int n_in,
                              void* d_out, int out_size, void* d_ws, size_t ws_size,
                              hipStream_t stream) {
  (void)in_sizes; (void)n_in; (void)out_size; (void)ws_size;
  const float* x     = (const float*)d_in[0];
  const float* cosb  = (const float*)d_in[1];
  const float* sinb  = (const float*)d_in[2];
  const float* Wqkv  = (const float*)d_in[3];
  const float* wq    = (const float*)d_in[4];
  const float* wk    = (const float*)d_in[5];
  const float* Wproj = (const float*)d_in[6];
  float* out = (float*)d_out;

  char* ws = (char*)d_ws;
  unsigned short* x_bf     = (unsigned short*)(ws);                 // 16 MB
  unsigned short* wqkv_bf  = (unsigned short*)(ws + 16777216);      // 48 MB
  unsigned short* wproj_bf = (unsigned short*)(ws + 67108864);      // 32 MB
  unsigned short* qkv      = (unsigned short*)(ws + 100663296);     // 24 MB (bf16)
  unsigned short* qr       = (unsigned short*)(ws + 150994944);     // 16 MB
  unsigned short* kr       = (unsigned short*)(ws + 167772160);     // 4 MB
  unsigned short* vt       = (unsigned short*)(ws + 171966464);     // 4 MB
  unsigned short* y        = (unsigned short*)(ws + 176160768);     // 16 MB

  cvt_all<<<49152, 256, 0, stream>>>(x, Wqkv, Wproj, x_bf, wqkv_bf, wproj_bf);
  gemm256<<<dim3(32, 8), 512, 0, stream>>>(x_bf, wqkv_bf, qkv, 2048, 6144, 4096);
  normrope<<<2048, 256, 0, stream>>>(qkv, cosb, sinb, wq, wk, qr, kr, vt);
  attn<<<dim3(32, 8), 512, 0, stream>>>(qr, kr, vt, y);
  gemm_bt<float><<<dim3(32, 16), 256, 0, stream>>>(y, wproj_bf, out, 2048, 4096, 4096);
}

// Round 3
// 479.931 us; speedup vs baseline: 1.0494x; 1.0001x over previous
//
#include <hip/hip_runtime.h>
#include <stdint.h>
#include <stddef.h>

#define T_SEQ 2048
#define WINDOW_SZ 1024

typedef __attribute__((ext_vector_type(4))) float f32x4;
typedef __attribute__((ext_vector_type(16))) float f32x16;
typedef __attribute__((ext_vector_type(8))) short s16x8;
typedef __attribute__((ext_vector_type(4))) short s16x4;

__device__ inline unsigned short f2bf(float f) {
  union { float f; unsigned u; } v; v.f = f;
  unsigned u = v.u;
  return (unsigned short)((u + 0x7fffu + ((u >> 16) & 1u)) >> 16);
}
__device__ inline float bf2f(unsigned short u) {
  union { unsigned u; float f; } v; v.u = ((unsigned)u) << 16; return v.f;
}

__device__ inline void gld_lds16(const unsigned short* g, unsigned short* l) {
  __builtin_amdgcn_global_load_lds((const __attribute__((address_space(1))) void*)g,
                                   (__attribute__((address_space(3))) void*)l, 16, 0, 0);
}

__device__ inline void store_out(float* p, float v) { *p = v; }
__device__ inline void store_out(unsigned short* p, float v) { *p = f2bf(v); }

// ---------------- fused fp32 -> bf16 convert for x, W_qkv, W_proj ----------------
__global__ __launch_bounds__(256) void cvt_all(const float* __restrict__ x,
                                               const float* __restrict__ wqkv,
                                               const float* __restrict__ wproj,
                                               unsigned short* __restrict__ x_bf,
                                               unsigned short* __restrict__ wqkv_bf,
                                               unsigned short* __restrict__ wproj_bf) {
  int i = blockIdx.x * 256 + threadIdx.x;  // 0 .. 12582912-1 float4s
  const float* s; unsigned short* d; int j;
  if (i < 2097152)       { s = x;     d = x_bf;     j = i; }
  else if (i < 8388608)  { s = wqkv;  d = wqkv_bf;  j = i - 2097152; }
  else                   { s = wproj; d = wproj_bf; j = i - 8388608; }
  float4 v = ((const float4*)s)[j];
  ushort4 o;
  o.x = f2bf(v.x); o.y = f2bf(v.y); o.z = f2bf(v.z); o.w = f2bf(v.w);
  ((ushort4*)d)[j] = o;
}

// ---------------- 128x128-tile bf16 GEMM (m97-class structure) — used for proj ----------------
template <typename OutT>
__global__ __launch_bounds__(256) void gemm_bt(const unsigned short* __restrict__ A,
                                               const unsigned short* __restrict__ Bt,
                                               OutT* __restrict__ C, int M, int N, int K) {
  __shared__ unsigned short As[128 * 64];  // row r chunk c at r*64+(c^(r&7))*8
  __shared__ unsigned short Bs[128 * 64];
  const int tid  = threadIdx.x;
  const int wave = tid >> 6, lane = tid & 63;
  const int l32 = lane & 31, khalf = lane >> 5;
  const int m0 = blockIdx.y << 7, n0 = blockIdx.x << 7;
  const int wr = (wave >> 1) << 6;
  const int wc = (wave & 1) << 6;
  const int srow = wave * 8 + (lane >> 3);
  const int gchunk0 = lane & 7;

  f32x16 acc[2][2] = {};

  for (int k0 = 0; k0 < K; k0 += 64) {
#pragma unroll
    for (int j = 0; j < 4; j++) {
      int r = j * 32 + srow;
      int gc = gchunk0 ^ (r & 7);
      gld_lds16(A  + (size_t)(m0 + r) * K + k0 + gc * 8, &As[(j * 32 + wave * 8) * 64]);
      gld_lds16(Bt + (size_t)(n0 + r) * K + k0 + gc * 8, &Bs[(j * 32 + wave * 8) * 64]);
    }
    __syncthreads();
#pragma unroll
    for (int s = 0; s < 4; s++) {
      s16x8 af[2], bfr[2];
      int chunk = s * 2 + khalf;
#pragma unroll
      for (int i = 0; i < 2; i++) {
        int ra = wr + i * 32 + l32;
        af[i]  = *(const s16x8*)&As[ra * 64 + ((chunk ^ (ra & 7)) * 8)];
        int rb = wc + i * 32 + l32;
        bfr[i] = *(const s16x8*)&Bs[rb * 64 + ((chunk ^ (rb & 7)) * 8)];
      }
#pragma unroll
      for (int mi = 0; mi < 2; mi++)
#pragma unroll
        for (int ni = 0; ni < 2; ni++)
          acc[mi][ni] = __builtin_amdgcn_mfma_f32_32x32x16_bf16(af[mi], bfr[ni], acc[mi][ni], 0, 0, 0);
    }
    __syncthreads();
  }
#pragma unroll
  for (int mi = 0; mi < 2; mi++)
#pragma unroll
    for (int ni = 0; ni < 2; ni++) {
      int col = n0 + wc + ni * 32 + l32;
      int rbase = m0 + wr + mi * 32 + 4 * khalf;
#pragma unroll
      for (int reg = 0; reg < 16; reg++) {
        int row = rbase + (reg & 3) + 8 * (reg >> 2);
        store_out(&C[(size_t)row * N + col], acc[mi][ni][reg]);
      }
    }
}

// ---------------- 256x192 8-wave phase-pipelined GEMM (T2+T3+T4+T5) — used for QKV ----------------
// BM=256, BN=192, BK=64 -> grid (32,8) = 256 blocks, exactly 1/CU.
// R3: A TRIPLE-buffered (deep prefetch). Steady-state tile u (A in Ab[u%3], B in Bb[u&1]):
//   phase0: read af(q0)+all bfr; stage A(u+2) half0 -> Ab[(u+2)%3]  (tile u-1's buffer — its
//           last af reads were consumed before tile u-1's final barrier, so overwrite is safe)
//   phase1: read af(q1);         stage A(u+2) half1
//   phase2: read af(q2);         stage B(u+2) half0 -> Bb[u&1]  (its readers finished at p0)
//   phase3: read af(q3);         stage B(u+2) half1 (1 load); vmcnt(7) keeps exactly this
//           tile's 7 loads {A(u+2)x4, B(u+2)x3} in flight and guarantees A(u+1)/B(u+1)
//           (issued a FULL TILE earlier — 4+ phases of latency cover) have landed.
//   Tail (u+2>=NT): vmcnt(0) drains (no staging left to count).
__device__ inline void stage_half(const unsigned short* __restrict__ g, int ldk,
                                  int grow0, int k0, unsigned short* lds,
                                  int wave, int lane) {
#pragma unroll
  for (int j = 0; j < 2; j++) {
    int rloc = j * 64 + wave * 8 + (lane >> 3);
    int lc = (lane & 7) ^ (rloc & 7);   // pre-swizzled global source, linear LDS dest
    gld_lds16(g + (size_t)(grow0 + rloc) * ldk + k0 + lc * 8,
              lds + (j * 64 + wave * 8) * 64);
  }
}
__device__ inline void stage_64(const unsigned short* __restrict__ g, int ldk,
                                int grow0, int k0, unsigned short* lds,
                                int wave, int lane) {
  int rloc = wave * 8 + (lane >> 3);
  int lc = (lane & 7) ^ (rloc & 7);
  gld_lds16(g + (size_t)(grow0 + rloc) * ldk + k0 + lc * 8,
            lds + (wave * 8) * 64);
}

__global__ __launch_bounds__(512, 2) void gemm256(const unsigned short* __restrict__ A,
                                                  const unsigned short* __restrict__ Bt,
                                                  unsigned short* __restrict__ C,
                                                  int M, int N, int K) {
  // LDS 144 KiB: A x3 (256x64 = 16384 elems each) at i*16384; B x2 (192x64 = 12288) at 49152+b*12288
  __shared__ unsigned short S[73728];
  const int tid = threadIdx.x, wave = tid >> 6, lane = tid & 63;
  const int quad = lane >> 4, l16 = lane & 15;
  const int wm = wave >> 2, wn = wave & 3;          // 2 x 4 wave grid; wave owns 128x48 of C
  const int m0 = blockIdx.y << 8, n0 = blockIdx.x * 192;
  const int NT = K >> 6;

  f32x4 acc[8][3] = {};

  unsigned short* const Ab0 = &S[0];
  unsigned short* const Bb0 = &S[49152];

  // prologue: A0 (4 loads), B0 (3), A1 (4), B1 (3); wait until A0+B0 landed (keep newest 7)
  stage_half(A,  K, m0,       0, Ab0,        wave, lane);
  stage_half(A,  K, m0 + 128, 0, Ab0 + 8192, wave, lane);
  stage_half(Bt, K, n0,       0, Bb0,        wave, lane);
  stage_64  (Bt, K, n0 + 128, 0, Bb0 + 8192, wave, lane);
  if (NT > 1) {
    stage_half(A,  K, m0,       64, Ab0 + 16384,        wave, lane);
    stage_half(A,  K, m0 + 128, 64, Ab0 + 16384 + 8192, wave, lane);
    stage_half(Bt, K, n0,       64, Bb0 + 12288,        wave, lane);
    stage_64  (Bt, K, n0 + 128, 64, Bb0 + 12288 + 8192, wave, lane);
    asm volatile("s_waitcnt vmcnt(7)" ::: "memory");
  } else {
    asm volatile("s_waitcnt vmcnt(0)" ::: "memory");
  }
  __builtin_amdgcn_s_barrier();
  asm volatile("" ::: "memory");

  int ac = 0;  // A buffer index of tile u (rotates mod 3)
  for (int u = 0; u < NT; ++u) {
    const unsigned short* Sa = Ab0 + ac * 16384;
    const unsigned short* Sb = Bb0 + (u & 1) * 12288;
    int an2 = ac + 2; if (an2 >= 3) an2 -= 3;                 // A buffer for tile u+2
    unsigned short* SaN = Ab0 + an2 * 16384;
    unsigned short* SbN = Bb0 + (u & 1) * 12288;              // B(u+2) reuses current B buffer
    s16x8 bfr[3][2];
#pragma unroll
    for (int p = 0; p < 4; ++p) {
      // --- ds-load register subtile (phase0: 10 reads, else 4) ---
      s16x8 af[2][2];
#pragma unroll
      for (int f = 0; f < 2; f++)
#pragma unroll
        for (int ks = 0; ks < 2; ks++) {
          int ra = wm * 128 + (p * 2 + f) * 16 + l16;
          af[f][ks] = *(const s16x8*)&Sa[ra * 64 + (((ks * 4 + quad) ^ (ra & 7)) * 8)];
        }
      if (p == 0) {
#pragma unroll
        for (int nf = 0; nf < 3; nf++)
#pragma unroll
          for (int ks = 0; ks < 2; ks++) {
            int rb = wn * 48 + nf * 16 + l16;
            bfr[nf][ks] = *(const s16x8*)&Sb[rb * 64 + (((ks * 4 + quad) ^ (rb & 7)) * 8)];
          }
      }
      // --- stage one half-tile (deep prefetch: A two tiles ahead) ---
      if (p == 0 && u + 2 < NT) stage_half(A,  K, m0,       (u + 2) << 6, SaN,        wave, lane);
      if (p == 1 && u + 2 < NT) stage_half(A,  K, m0 + 128, (u + 2) << 6, SaN + 8192, wave, lane);
      if (p == 2 && u + 2 < NT) stage_half(Bt, K, n0,       (u + 2) << 6, SbN,        wave, lane);
      if (p == 3 && u + 2 < NT) stage_64  (Bt, K, n0 + 128, (u + 2) << 6, SbN + 8192, wave, lane);

      asm volatile("" ::: "memory");
      __builtin_amdgcn_s_barrier();
      asm volatile("" ::: "memory");
      // --- 12 MFMA: C-quadrant (2 M-frags x 3 N-frags) x K=64 ---
      __builtin_amdgcn_s_setprio(1);
#pragma unroll
      for (int f = 0; f < 2; f++)
#pragma unroll
        for (int nf = 0; nf < 3; nf++)
#pragma unroll
          for (int ks = 0; ks < 2; ks++)
            acc[p * 2 + f][nf] = __builtin_amdgcn_mfma_f32_16x16x32_bf16(
                af[f][ks], bfr[nf][ks], acc[p * 2 + f][nf], 0, 0, 0);
      __builtin_amdgcn_s_setprio(0);
      if (p == 3) {
        if (u + 2 < NT) asm volatile("s_waitcnt vmcnt(7)" ::: "memory");
        else            asm volatile("s_waitcnt vmcnt(0)" ::: "memory");
      }
      asm volatile("" ::: "memory");
      __builtin_amdgcn_s_barrier();
      asm volatile("" ::: "memory");
    }
    ac = (ac == 2) ? 0 : ac + 1;
  }
  // C/D 16x16: col = lane&15, row = quad*4 + reg  [m89]
#pragma unroll
  for (int mf = 0; mf < 8; mf++)
#pragma unroll
    for (int nf = 0; nf < 3; nf++) {
      const int row0 = m0 + wm * 128 + mf * 16 + quad * 4;
      const int col  = n0 + wn * 48 + nf * 16 + l16;
#pragma unroll
      for (int r = 0; r < 4; r++)
        C[(size_t)(row0 + r) * N + col] = f2bf(acc[mf][nf][r]);
    }
}

// ---------------- fused RMSNorm + RoPE + layout (one block per token) ----------------
__global__ __launch_bounds__(256) void normrope(const unsigned short* __restrict__ qkv,
                                                const float* __restrict__ cosb,
                                                const float* __restrict__ sinb,
                                                const float* __restrict__ wq,
                                                const float* __restrict__ wk,
                                                unsigned short* __restrict__ qr,
                                                unsigned short* __restrict__ kr,
                                                unsigned short* __restrict__ vt) {
  const int t = blockIdx.x, tid = threadIdx.x;
  const unsigned short* row = qkv + (size_t)t * 6144;
  float sq = 0.f, sk = 0.f;
  {
    s16x8 a = *(const s16x8*)&row[tid * 16];
    s16x8 b = *(const s16x8*)&row[tid * 16 + 8];
#pragma unroll
    for (int j = 0; j < 8; j++) {
      float fa = bf2f((unsigned short)a[j]), fb = bf2f((unsigned short)b[j]);
      sq += fa * fa + fb * fb;
    }
  }
  {
    s16x4 a = *(const s16x4*)&row[4096 + tid * 4];
#pragma unroll
    for (int j = 0; j < 4; j++) {
      float fa = bf2f((unsigned short)a[j]);
      sk += fa * fa;
    }
  }
#pragma unroll
  for (int off = 32; off; off >>= 1) { sq += __shfl_xor(sq, off); sk += __shfl_xor(sk, off); }
  __shared__ float red[8];
  if ((tid & 63) == 0) { red[tid >> 6] = sq; red[4 + (tid >> 6)] = sk; }
  __syncthreads();
  sq = red[0] + red[1] + red[2] + red[3];
  sk = red[4] + red[5] + red[6] + red[7];
  const float rq = rsqrtf(sq * (1.f / 4096.f) + 1e-5f) * (0.08838834764831845f * 1.4426950408889634f);
  const float rk = rsqrtf(sk * (1.f / 1024.f) + 1e-5f);
  for (int i = tid; i < 4096; i += 256) {
    int h = i >> 7, d = i & 127;
    int pd = (d < 64) ? d + 64 : d - 64;
    float val = bf2f(row[i]) * rq * wq[i];
    float pv  = bf2f(row[(h << 7) + pd]) * rq * wq[(h << 7) + pd];
    float rot = (d < 64) ? -pv : pv;
    float o = val * cosb[t * 128 + d] + rot * sinb[t * 128 + d];
    qr[(size_t)h * T_SEQ * 128 + t * 128 + d] = f2bf(o);
  }
  for (int i = tid; i < 1024; i += 256) {
    int g = i >> 7, d = i & 127;
    int pd = (d < 64) ? d + 64 : d - 64;
    float val = bf2f(row[4096 + i]) * rk * wk[i];
    float pv  = bf2f(row[4096 + (g << 7) + pd]) * rk * wk[(g << 7) + pd];
    float rot = (d < 64) ? -pv : pv;
    float o = val * cosb[t * 128 + d] + rot * sinb[t * 128 + d];
    kr[(size_t)g * T_SEQ * 128 + t * 128 + d] = f2bf(o);
  }
  for (int i = tid; i < 1024; i += 256) {
    int g = i >> 7, d = i & 127;
    vt[(size_t)g * 128 * T_SEQ + (size_t)d * T_SEQ + t] = row[5120 + i];
  }
}

// ---------------- flash attention, sliding window, block-shared LDS K/V ----------------
__global__ __launch_bounds__(512, 2) void attn(const unsigned short* __restrict__ Q,
                                               const unsigned short* __restrict__ Kb,
                                               const unsigned short* __restrict__ Vt,
                                               unsigned short* __restrict__ Y) {
  __shared__ unsigned short Kbuf[2][64 * 128];
  __shared__ unsigned short Vbuf[2][128 * 64];
  __shared__ unsigned short Pbuf[8][2][16 * 72];
  const int qb = blockIdx.x, g = blockIdx.y;
  const int tid = threadIdx.x, wave = tid >> 6, lane = tid & 63;
  const int quad = lane >> 4, l16 = lane & 15;
  const int h = g * 4 + (wave >> 1);
  const int qbase = qb * 64;
  const int q0 = qbase + (wave & 1) * 32;
  const unsigned short* Qh = Q + (size_t)h * T_SEQ * 128;
  const unsigned short* Kg = Kb + (size_t)g * T_SEQ * 128;
  const unsigned short* Vg = Vt + (size_t)g * 128 * T_SEQ;

  s16x8 aq[2][4];
#pragma unroll
  for (int qt = 0; qt < 2; qt++)
#pragma unroll
    for (int ks = 0; ks < 4; ks++)
      aq[qt][ks] = *(const s16x8*)&Qh[(size_t)(q0 + qt * 16 + l16) * 128 + ks * 32 + quad * 8];

  f32x4 acc[2][8] = {};
  float lrow[2][4] = {};

  int lo = qbase - (WINDOW_SZ - 1);
  if (lo < 0) lo = 0;
  lo &= ~63;

#define STAGE_CHUNK(buf, kkv)                                                        \
  {                                                                                  \
    int kk_ = (kkv);                                                                 \
    _Pragma("unroll")                                                                \
    for (int j = 0; j < 2; j++) {                                                    \
      int rloc = wave * 8 + j * 4 + (lane >> 4);                                     \
      int oct = (lane & 15) ^ (rloc & 15);                                           \
      gld_lds16(Kg + (size_t)(kk_ + rloc) * 128 + oct * 8,                           \
                &Kbuf[buf][(wave * 8 + j * 4) * 128]);                               \
    }                                                                                \
    _Pragma("unroll")                                                                \
    for (int j = 0; j < 2; j++) {                                                    \
      int dloc = wave * 16 + j * 8 + (lane >> 3);                                    \
      int oct = (lane & 7) ^ (dloc & 7);                                             \
      gld_lds16(Vg + (size_t)dloc * T_SEQ + kk_ + oct * 8,                           \
                &Vbuf[buf][(wave * 16 + j * 8) * 64]);                               \
    }                                                                                \
  }

  STAGE_CHUNK(0, lo);
  int ib = 0;
  for (int kk = lo; kk < qbase + 64; kk += 64, ib ^= 1) {
    __syncthreads();
    if (kk + 64 < qbase + 64) STAGE_CHUNK(ib ^ 1, kk + 64);
    if (kk > q0 + 31 || kk + 63 < q0 - (WINDOW_SZ - 1)) continue;
    const unsigned short* kb = Kbuf[ib];
    const unsigned short* vb = Vbuf[ib];
    f32x4 sc[2][4] = {};
    __builtin_amdgcn_s_setprio(1);
#pragma unroll
    for (int ks = 0; ks < 4; ks++) {
#pragma unroll
      for (int ci = 0; ci < 4; ci++) {
        s16x8 bk = *(const s16x8*)&kb[(ci * 16 + l16) * 128 + (((ks * 4 + quad) ^ l16) * 8)];
        sc[0][ci] = __builtin_amdgcn_mfma_f32_16x16x32_bf16(aq[0][ks], bk, sc[0][ci], 0, 0, 0);
        sc[1][ci] = __builtin_amdgcn_mfma_f32_16x16x32_bf16(aq[1][ks], bk, sc[1][ci], 0, 0, 0);
      }
    }
    __builtin_amdgcn_s_setprio(0);
#pragma unroll
    for (int qt = 0; qt < 2; qt++)
#pragma unroll
      for (int ci = 0; ci < 4; ci++) {
        int col = kk + ci * 16 + l16;
#pragma unroll
        for (int r = 0; r < 4; r++) {
          int irow = q0 + qt * 16 + quad * 4 + r;
          unsigned dd = (unsigned)(irow - col);
          float e = (dd < (unsigned)WINDOW_SZ) ? exp2f(sc[qt][ci][r]) : 0.f;
          lrow[qt][r] += e;
          Pbuf[wave][qt][(quad * 4 + r) * 72 + ci * 16 + l16] = f2bf(e);
        }
      }
    __builtin_amdgcn_s_setprio(1);
#pragma unroll
    for (int c = 0; c < 2; c++) {
      s16x8 pa0 = *(const s16x8*)&Pbuf[wave][0][l16 * 72 + c * 32 + quad * 8];
      s16x8 pa1 = *(const s16x8*)&Pbuf[wave][1][l16 * 72 + c * 32 + quad * 8];
#pragma unroll
      for (int n = 0; n < 8; n++) {
        s16x8 bv = *(const s16x8*)&vb[(n * 16 + l16) * 64 + (((c * 4 + quad) ^ (l16 & 7)) * 8)];
        acc[0][n] = __builtin_amdgcn_mfma_f32_16x16x32_bf16(pa0, bv, acc[0][n], 0, 0, 0);
        acc[1][n] = __builtin_amdgcn_mfma_f32_16x16x32_bf16(pa1, bv, acc[1][n], 0, 0, 0);
      }
    }
    __builtin_amdgcn_s_setprio(0);
  }
#undef STAGE_CHUNK
#pragma unroll
  for (int qt = 0; qt < 2; qt++)
#pragma unroll
    for (int r = 0; r < 4; r++) {
#pragma unroll
      for (int off = 8; off; off >>= 1) lrow[qt][r] += __shfl_xor(lrow[qt][r], off);
      lrow[qt][r] = 1.f / lrow[qt][r];
    }
#pragma unroll
  for (int qt = 0; qt < 2; qt++)
#pragma unroll
    for (int n = 0; n < 8; n++)
#pragma unroll
      for (int r = 0; r < 4; r++) {
        int irow = q0 + qt * 16 + quad * 4 + r;
        Y[(size_t)irow * 4096 + h * 128 + n * 16 + l16] = f2bf(acc[qt][n][r] * lrow[qt][r]);
      }
}

extern "C" void kernel_launch(void* const* d_in, const int* in_sizes, int n_in,
                              void* d_out, int out_size, void* d_ws, size_t ws_size,
                              hipStream_t stream) {
  (void)in_sizes; (void)n_in; (void)out_size; (void)ws_size;
  const float* x     = (const float*)d_in[0];
  const float* cosb  = (const float*)d_in[1];
  const float* sinb  = (const float*)d_in[2];
  const float* Wqkv  = (const float*)d_in[3];
  const float* wq    = (const float*)d_in[4];
  const float* wk    = (const float*)d_in[5];
  const float* Wproj = (const float*)d_in[6];
  float* out = (float*)d_out;

  char* ws = (char*)d_ws;
  unsigned short* x_bf     = (unsigned short*)(ws);                 // 16 MB
  unsigned short* wqkv_bf  = (unsigned short*)(ws + 16777216);      // 48 MB
  unsigned short* wproj_bf = (unsigned short*)(ws + 67108864);      // 32 MB
  unsigned short* qkv      = (unsigned short*)(ws + 100663296);     // 24 MB (bf16)
  unsigned short* qr       = (unsigned short*)(ws + 150994944);     // 16 MB
  unsigned short* kr       = (unsigned short*)(ws + 167772160);     // 4 MB
  unsigned short* vt       = (unsigned short*)(ws + 171966464);     // 4 MB
  unsigned short* y        = (unsigned short*)(ws + 176160768);     // 16 MB

  cvt_all<<<49152, 256, 0, stream>>>(x, Wqkv, Wproj, x_bf, wqkv_bf, wproj_bf);
  gemm256<<<dim3(32, 8), 512, 0, stream>>>(x_bf, wqkv_bf, qkv, 2048, 6144, 4096);
  normrope<<<2048, 256, 0, stream>>>(qkv, cosb, sinb, wq, wk, qr, kr, vt);
  attn<<<dim3(32, 8), 512, 0, stream>>>(qr, kr, vt, y);
  gemm_bt<float><<<dim3(32, 16), 256, 0, stream>>>(y, wproj_bf, out, 2048, 4096, 4096);
}

// Round 4
// 477.498 us; speedup vs baseline: 1.0548x; 1.0051x over previous
//
#include <hip/hip_runtime.h>
#include <stdint.h>
#include <stddef.h>

#define T_SEQ 2048
#define WINDOW_SZ 1024

typedef __attribute__((ext_vector_type(4))) float f32x4;
typedef __attribute__((ext_vector_type(16))) float f32x16;
typedef __attribute__((ext_vector_type(8))) short s16x8;
typedef __attribute__((ext_vector_type(4))) short s16x4;

__device__ inline unsigned short f2bf(float f) {
  union { float f; unsigned u; } v; v.f = f;
  unsigned u = v.u;
  return (unsigned short)((u + 0x7fffu + ((u >> 16) & 1u)) >> 16);
}
__device__ inline float bf2f(unsigned short u) {
  union { unsigned u; float f; } v; v.u = ((unsigned)u) << 16; return v.f;
}

__device__ inline void gld_lds16(const unsigned short* g, unsigned short* l) {
  __builtin_amdgcn_global_load_lds((const __attribute__((address_space(1))) void*)g,
                                   (__attribute__((address_space(3))) void*)l, 16, 0, 0);
}

__device__ inline void store_out(float* p, float v) { *p = v; }
__device__ inline void store_out(unsigned short* p, float v) { *p = f2bf(v); }

// ---------------- fused fp32 -> bf16 convert for x, W_qkv, W_proj ----------------
__global__ __launch_bounds__(256) void cvt_all(const float* __restrict__ x,
                                               const float* __restrict__ wqkv,
                                               const float* __restrict__ wproj,
                                               unsigned short* __restrict__ x_bf,
                                               unsigned short* __restrict__ wqkv_bf,
                                               unsigned short* __restrict__ wproj_bf) {
  int i = blockIdx.x * 256 + threadIdx.x;  // 0 .. 12582912-1 float4s
  const float* s; unsigned short* d; int j;
  if (i < 2097152)       { s = x;     d = x_bf;     j = i; }
  else if (i < 8388608)  { s = wqkv;  d = wqkv_bf;  j = i - 2097152; }
  else                   { s = wproj; d = wproj_bf; j = i - 8388608; }
  float4 v = ((const float4*)s)[j];
  ushort4 o;
  o.x = f2bf(v.x); o.y = f2bf(v.y); o.z = f2bf(v.z); o.w = f2bf(v.w);
  ((ushort4*)d)[j] = o;
}

// ---------------- 128x128-tile bf16 GEMM (m97-class structure) — used for proj ----------------
template <typename OutT>
__global__ __launch_bounds__(256) void gemm_bt(const unsigned short* __restrict__ A,
                                               const unsigned short* __restrict__ Bt,
                                               OutT* __restrict__ C, int M, int N, int K) {
  __shared__ unsigned short As[128 * 64];  // row r chunk c at r*64+(c^(r&7))*8
  __shared__ unsigned short Bs[128 * 64];
  const int tid  = threadIdx.x;
  const int wave = tid >> 6, lane = tid & 63;
  const int l32 = lane & 31, khalf = lane >> 5;
  const int m0 = blockIdx.y << 7, n0 = blockIdx.x << 7;
  const int wr = (wave >> 1) << 6;
  const int wc = (wave & 1) << 6;
  const int srow = wave * 8 + (lane >> 3);
  const int gchunk0 = lane & 7;

  f32x16 acc[2][2] = {};

  for (int k0 = 0; k0 < K; k0 += 64) {
#pragma unroll
    for (int j = 0; j < 4; j++) {
      int r = j * 32 + srow;
      int gc = gchunk0 ^ (r & 7);
      gld_lds16(A  + (size_t)(m0 + r) * K + k0 + gc * 8, &As[(j * 32 + wave * 8) * 64]);
      gld_lds16(Bt + (size_t)(n0 + r) * K + k0 + gc * 8, &Bs[(j * 32 + wave * 8) * 64]);
    }
    __syncthreads();
#pragma unroll
    for (int s = 0; s < 4; s++) {
      s16x8 af[2], bfr[2];
      int chunk = s * 2 + khalf;
#pragma unroll
      for (int i = 0; i < 2; i++) {
        int ra = wr + i * 32 + l32;
        af[i]  = *(const s16x8*)&As[ra * 64 + ((chunk ^ (ra & 7)) * 8)];
        int rb = wc + i * 32 + l32;
        bfr[i] = *(const s16x8*)&Bs[rb * 64 + ((chunk ^ (rb & 7)) * 8)];
      }
#pragma unroll
      for (int mi = 0; mi < 2; mi++)
#pragma unroll
        for (int ni = 0; ni < 2; ni++)
          acc[mi][ni] = __builtin_amdgcn_mfma_f32_32x32x16_bf16(af[mi], bfr[ni], acc[mi][ni], 0, 0, 0);
    }
    __syncthreads();
  }
#pragma unroll
  for (int mi = 0; mi < 2; mi++)
#pragma unroll
    for (int ni = 0; ni < 2; ni++) {
      int col = n0 + wc + ni * 32 + l32;
      int rbase = m0 + wr + mi * 32 + 4 * khalf;
#pragma unroll
      for (int reg = 0; reg < 16; reg++) {
        int row = rbase + (reg & 3) + 8 * (reg >> 2);
        store_out(&C[(size_t)row * N + col], acc[mi][ni][reg]);
      }
    }
}

// ---------------- 256x192 8-wave phase-pipelined GEMM (T2+T3+T4+T5) — used for QKV ----------------
// BM=256, BN=192, BK=64 -> grid (32,8) = 256 blocks, exactly 1/CU.
// R4: 2 phases per K-tile (24 MFMA each) — halves barrier-pair count per MFMA.
// A triple-buffered (required: A(u+2) staged at p0 while A(u),A(u+1) live).
// Steady-state tile u (A in Ab[u%3], B in Bb[u&1]):
//   phase0: read af(Mfrags 0-3, 8 reads) + all bfr (6 reads); stage A(u+2) both halves
//           (4 loads) -> Ab[(u+2)%3]; barrier; 24 MFMA; barrier.
//   phase1: read af(Mfrags 4-7, 8 reads); stage B(u+2) (3 loads) -> Bb[u&1] (its only
//           readers finished at p0); barrier; 24 MFMA; vmcnt(7) — keeps exactly this
//           tile's 7 loads {A(u+2)x4, B(u+2)x3} in flight, guarantees A(u+1)/B(u+1)
//           (issued one full tile earlier) landed; barrier.
//   Tail (u+2>=NT): vmcnt(0) drains (nothing newer to count).
__device__ inline void stage_half(const unsigned short* __restrict__ g, int ldk,
                                  int grow0, int k0, unsigned short* lds,
                                  int wave, int lane) {
#pragma unroll
  for (int j = 0; j < 2; j++) {
    int rloc = j * 64 + wave * 8 + (lane >> 3);
    int lc = (lane & 7) ^ (rloc & 7);   // pre-swizzled global source, linear LDS dest
    gld_lds16(g + (size_t)(grow0 + rloc) * ldk + k0 + lc * 8,
              lds + (j * 64 + wave * 8) * 64);
  }
}
__device__ inline void stage_64(const unsigned short* __restrict__ g, int ldk,
                                int grow0, int k0, unsigned short* lds,
                                int wave, int lane) {
  int rloc = wave * 8 + (lane >> 3);
  int lc = (lane & 7) ^ (rloc & 7);
  gld_lds16(g + (size_t)(grow0 + rloc) * ldk + k0 + lc * 8,
            lds + (wave * 8) * 64);
}

__global__ __launch_bounds__(512, 2) void gemm256(const unsigned short* __restrict__ A,
                                                  const unsigned short* __restrict__ Bt,
                                                  unsigned short* __restrict__ C,
                                                  int M, int N, int K) {
  // LDS 144 KiB: A x3 (256x64 = 16384 elems each) at i*16384; B x2 (192x64 = 12288) at 49152+b*12288
  __shared__ unsigned short S[73728];
  const int tid = threadIdx.x, wave = tid >> 6, lane = tid & 63;
  const int quad = lane >> 4, l16 = lane & 15;
  const int wm = wave >> 2, wn = wave & 3;          // 2 x 4 wave grid; wave owns 128x48 of C
  const int m0 = blockIdx.y << 8, n0 = blockIdx.x * 192;
  const int NT = K >> 6;

  f32x4 acc[8][3] = {};

  unsigned short* const Ab0 = &S[0];
  unsigned short* const Bb0 = &S[49152];

  // prologue: A0 (4 loads), B0 (3), A1 (4), B1 (3); wait until A0+B0 landed (keep newest 7)
  stage_half(A,  K, m0,       0, Ab0,        wave, lane);
  stage_half(A,  K, m0 + 128, 0, Ab0 + 8192, wave, lane);
  stage_half(Bt, K, n0,       0, Bb0,        wave, lane);
  stage_64  (Bt, K, n0 + 128, 0, Bb0 + 8192, wave, lane);
  if (NT > 1) {
    stage_half(A,  K, m0,       64, Ab0 + 16384,        wave, lane);
    stage_half(A,  K, m0 + 128, 64, Ab0 + 16384 + 8192, wave, lane);
    stage_half(Bt, K, n0,       64, Bb0 + 12288,        wave, lane);
    stage_64  (Bt, K, n0 + 128, 64, Bb0 + 12288 + 8192, wave, lane);
    asm volatile("s_waitcnt vmcnt(7)" ::: "memory");
  } else {
    asm volatile("s_waitcnt vmcnt(0)" ::: "memory");
  }
  __builtin_amdgcn_s_barrier();
  asm volatile("" ::: "memory");

  int ac = 0;  // A buffer index of tile u (rotates mod 3)
  for (int u = 0; u < NT; ++u) {
    const unsigned short* Sa = Ab0 + ac * 16384;
    const unsigned short* Sb = Bb0 + (u & 1) * 12288;
    int an2 = ac + 2; if (an2 >= 3) an2 -= 3;                 // A buffer for tile u+2
    unsigned short* SaN = Ab0 + an2 * 16384;
    unsigned short* SbN = Bb0 + (u & 1) * 12288;              // B(u+2) reuses current B buffer
    s16x8 bfr[3][2];
#pragma unroll
    for (int p = 0; p < 2; ++p) {
      // --- ds-load register subtile (phase0: 14 reads, phase1: 8) ---
      s16x8 af[4][2];
#pragma unroll
      for (int f = 0; f < 4; f++)
#pragma unroll
        for (int ks = 0; ks < 2; ks++) {
          int ra = wm * 128 + (p * 4 + f) * 16 + l16;
          af[f][ks] = *(const s16x8*)&Sa[ra * 64 + (((ks * 4 + quad) ^ (ra & 7)) * 8)];
        }
      if (p == 0) {
#pragma unroll
        for (int nf = 0; nf < 3; nf++)
#pragma unroll
          for (int ks = 0; ks < 2; ks++) {
            int rb = wn * 48 + nf * 16 + l16;
            bfr[nf][ks] = *(const s16x8*)&Sb[rb * 64 + (((ks * 4 + quad) ^ (rb & 7)) * 8)];
          }
        if (u + 2 < NT) {
          stage_half(A, K, m0,       (u + 2) << 6, SaN,        wave, lane);
          stage_half(A, K, m0 + 128, (u + 2) << 6, SaN + 8192, wave, lane);
        }
      } else {
        if (u + 2 < NT) {
          stage_half(Bt, K, n0,       (u + 2) << 6, SbN,        wave, lane);
          stage_64  (Bt, K, n0 + 128, (u + 2) << 6, SbN + 8192, wave, lane);
        }
      }

      asm volatile("" ::: "memory");
      __builtin_amdgcn_s_barrier();
      asm volatile("" ::: "memory");
      // --- 24 MFMA: 4 M-frags x 3 N-frags x K=64 ---
      __builtin_amdgcn_s_setprio(1);
#pragma unroll
      for (int f = 0; f < 4; f++)
#pragma unroll
        for (int nf = 0; nf < 3; nf++)
#pragma unroll
          for (int ks = 0; ks < 2; ks++)
            acc[p * 4 + f][nf] = __builtin_amdgcn_mfma_f32_16x16x32_bf16(
                af[f][ks], bfr[nf][ks], acc[p * 4 + f][nf], 0, 0, 0);
      __builtin_amdgcn_s_setprio(0);
      if (p == 1) {
        if (u + 2 < NT) asm volatile("s_waitcnt vmcnt(7)" ::: "memory");
        else            asm volatile("s_waitcnt vmcnt(0)" ::: "memory");
      }
      asm volatile("" ::: "memory");
      __builtin_amdgcn_s_barrier();
      asm volatile("" ::: "memory");
    }
    ac = (ac == 2) ? 0 : ac + 1;
  }
  // C/D 16x16: col = lane&15, row = quad*4 + reg  [m89]
#pragma unroll
  for (int mf = 0; mf < 8; mf++)
#pragma unroll
    for (int nf = 0; nf < 3; nf++) {
      const int row0 = m0 + wm * 128 + mf * 16 + quad * 4;
      const int col  = n0 + wn * 48 + nf * 16 + l16;
#pragma unroll
      for (int r = 0; r < 4; r++)
        C[(size_t)(row0 + r) * N + col] = f2bf(acc[mf][nf][r]);
    }
}

// ---------------- fused RMSNorm + RoPE + layout (one block per token) ----------------
__global__ __launch_bounds__(256) void normrope(const unsigned short* __restrict__ qkv,
                                                const float* __restrict__ cosb,
                                                const float* __restrict__ sinb,
                                                const float* __restrict__ wq,
                                                const float* __restrict__ wk,
                                                unsigned short* __restrict__ qr,
                                                unsigned short* __restrict__ kr,
                                                unsigned short* __restrict__ vt) {
  const int t = blockIdx.x, tid = threadIdx.x;
  const unsigned short* row = qkv + (size_t)t * 6144;
  float sq = 0.f, sk = 0.f;
  {
    s16x8 a = *(const s16x8*)&row[tid * 16];
    s16x8 b = *(const s16x8*)&row[tid * 16 + 8];
#pragma unroll
    for (int j = 0; j < 8; j++) {
      float fa = bf2f((unsigned short)a[j]), fb = bf2f((unsigned short)b[j]);
      sq += fa * fa + fb * fb;
    }
  }
  {
    s16x4 a = *(const s16x4*)&row[4096 + tid * 4];
#pragma unroll
    for (int j = 0; j < 4; j++) {
      float fa = bf2f((unsigned short)a[j]);
      sk += fa * fa;
    }
  }
#pragma unroll
  for (int off = 32; off; off >>= 1) { sq += __shfl_xor(sq, off); sk += __shfl_xor(sk, off); }
  __shared__ float red[8];
  if ((tid & 63) == 0) { red[tid >> 6] = sq; red[4 + (tid >> 6)] = sk; }
  __syncthreads();
  sq = red[0] + red[1] + red[2] + red[3];
  sk = red[4] + red[5] + red[6] + red[7];
  const float rq = rsqrtf(sq * (1.f / 4096.f) + 1e-5f) * (0.08838834764831845f * 1.4426950408889634f);
  const float rk = rsqrtf(sk * (1.f / 1024.f) + 1e-5f);
  for (int i = tid; i < 4096; i += 256) {
    int h = i >> 7, d = i & 127;
    int pd = (d < 64) ? d + 64 : d - 64;
    float val = bf2f(row[i]) * rq * wq[i];
    float pv  = bf2f(row[(h << 7) + pd]) * rq * wq[(h << 7) + pd];
    float rot = (d < 64) ? -pv : pv;
    float o = val * cosb[t * 128 + d] + rot * sinb[t * 128 + d];
    qr[(size_t)h * T_SEQ * 128 + t * 128 + d] = f2bf(o);
  }
  for (int i = tid; i < 1024; i += 256) {
    int g = i >> 7, d = i & 127;
    int pd = (d < 64) ? d + 64 : d - 64;
    float val = bf2f(row[4096 + i]) * rk * wk[i];
    float pv  = bf2f(row[4096 + (g << 7) + pd]) * rk * wk[(g << 7) + pd];
    float rot = (d < 64) ? -pv : pv;
    float o = val * cosb[t * 128 + d] + rot * sinb[t * 128 + d];
    kr[(size_t)g * T_SEQ * 128 + t * 128 + d] = f2bf(o);
  }
  for (int i = tid; i < 1024; i += 256) {
    int g = i >> 7, d = i & 127;
    vt[(size_t)g * 128 * T_SEQ + (size_t)d * T_SEQ + t] = row[5120 + i];
  }
}

// ---------------- flash attention, sliding window, block-shared LDS K/V ----------------
__global__ __launch_bounds__(512, 2) void attn(const unsigned short* __restrict__ Q,
                                               const unsigned short* __restrict__ Kb,
                                               const unsigned short* __restrict__ Vt,
                                               unsigned short* __restrict__ Y) {
  __shared__ unsigned short Kbuf[2][64 * 128];
  __shared__ unsigned short Vbuf[2][128 * 64];
  __shared__ unsigned short Pbuf[8][2][16 * 72];
  const int qb = blockIdx.x, g = blockIdx.y;
  const int tid = threadIdx.x, wave = tid >> 6, lane = tid & 63;
  const int quad = lane >> 4, l16 = lane & 15;
  const int h = g * 4 + (wave >> 1);
  const int qbase = qb * 64;
  const int q0 = qbase + (wave & 1) * 32;
  const unsigned short* Qh = Q + (size_t)h * T_SEQ * 128;
  const unsigned short* Kg = Kb + (size_t)g * T_SEQ * 128;
  const unsigned short* Vg = Vt + (size_t)g * 128 * T_SEQ;

  s16x8 aq[2][4];
#pragma unroll
  for (int qt = 0; qt < 2; qt++)
#pragma unroll
    for (int ks = 0; ks < 4; ks++)
      aq[qt][ks] = *(const s16x8*)&Qh[(size_t)(q0 + qt * 16 + l16) * 128 + ks * 32 + quad * 8];

  f32x4 acc[2][8] = {};
  float lrow[2][4] = {};

  int lo = qbase - (WINDOW_SZ - 1);
  if (lo < 0) lo = 0;
  lo &= ~63;

#define STAGE_CHUNK(buf, kkv)                                                        \
  {                                                                                  \
    int kk_ = (kkv);                                                                 \
    _Pragma("unroll")                                                                \
    for (int j = 0; j < 2; j++) {                                                    \
      int rloc = wave * 8 + j * 4 + (lane >> 4);                                     \
      int oct = (lane & 15) ^ (rloc & 15);                                           \
      gld_lds16(Kg + (size_t)(kk_ + rloc) * 128 + oct * 8,                           \
                &Kbuf[buf][(wave * 8 + j * 4) * 128]);                               \
    }                                                                                \
    _Pragma("unroll")                                                                \
    for (int j = 0; j < 2; j++) {                                                    \
      int dloc = wave * 16 + j * 8 + (lane >> 3);                                    \
      int oct = (lane & 7) ^ (dloc & 7);                                             \
      gld_lds16(Vg + (size_t)dloc * T_SEQ + kk_ + oct * 8,                           \
                &Vbuf[buf][(wave * 16 + j * 8) * 64]);                               \
    }                                                                                \
  }

  STAGE_CHUNK(0, lo);
  int ib = 0;
  for (int kk = lo; kk < qbase + 64; kk += 64, ib ^= 1) {
    __syncthreads();
    if (kk + 64 < qbase + 64) STAGE_CHUNK(ib ^ 1, kk + 64);
    if (kk > q0 + 31 || kk + 63 < q0 - (WINDOW_SZ - 1)) continue;
    const unsigned short* kb = Kbuf[ib];
    const unsigned short* vb = Vbuf[ib];
    f32x4 sc[2][4] = {};
    __builtin_amdgcn_s_setprio(1);
#pragma unroll
    for (int ks = 0; ks < 4; ks++) {
#pragma unroll
      for (int ci = 0; ci < 4; ci++) {
        s16x8 bk = *(const s16x8*)&kb[(ci * 16 + l16) * 128 + (((ks * 4 + quad) ^ l16) * 8)];
        sc[0][ci] = __builtin_amdgcn_mfma_f32_16x16x32_bf16(aq[0][ks], bk, sc[0][ci], 0, 0, 0);
        sc[1][ci] = __builtin_amdgcn_mfma_f32_16x16x32_bf16(aq[1][ks], bk, sc[1][ci], 0, 0, 0);
      }
    }
    __builtin_amdgcn_s_setprio(0);
#pragma unroll
    for (int qt = 0; qt < 2; qt++)
#pragma unroll
      for (int ci = 0; ci < 4; ci++) {
        int col = kk + ci * 16 + l16;
#pragma unroll
        for (int r = 0; r < 4; r++) {
          int irow = q0 + qt * 16 + quad * 4 + r;
          unsigned dd = (unsigned)(irow - col);
          float e = (dd < (unsigned)WINDOW_SZ) ? exp2f(sc[qt][ci][r]) : 0.f;
          lrow[qt][r] += e;
          Pbuf[wave][qt][(quad * 4 + r) * 72 + ci * 16 + l16] = f2bf(e);
        }
      }
    __builtin_amdgcn_s_setprio(1);
#pragma unroll
    for (int c = 0; c < 2; c++) {
      s16x8 pa0 = *(const s16x8*)&Pbuf[wave][0][l16 * 72 + c * 32 + quad * 8];
      s16x8 pa1 = *(const s16x8*)&Pbuf[wave][1][l16 * 72 + c * 32 + quad * 8];
#pragma unroll
      for (int n = 0; n < 8; n++) {
        s16x8 bv = *(const s16x8*)&vb[(n * 16 + l16) * 64 + (((c * 4 + quad) ^ (l16 & 7)) * 8)];
        acc[0][n] = __builtin_amdgcn_mfma_f32_16x16x32_bf16(pa0, bv, acc[0][n], 0, 0, 0);
        acc[1][n] = __builtin_amdgcn_mfma_f32_16x16x32_bf16(pa1, bv, acc[1][n], 0, 0, 0);
      }
    }
    __builtin_amdgcn_s_setprio(0);
  }
#undef STAGE_CHUNK
#pragma unroll
  for (int qt = 0; qt < 2; qt++)
#pragma unroll
    for (int r = 0; r < 4; r++) {
#pragma unroll
      for (int off = 8; off; off >>= 1) lrow[qt][r] += __shfl_xor(lrow[qt][r], off);
      lrow[qt][r] = 1.f / lrow[qt][r];
    }
#pragma unroll
  for (int qt = 0; qt < 2; qt++)
#pragma unroll
    for (int n = 0; n < 8; n++)
#pragma unroll
      for (int r = 0; r < 4; r++) {
        int irow = q0 + qt * 16 + quad * 4 + r;
        Y[(size_t)irow * 4096 + h * 128 + n * 16 + l16] = f2bf(acc[qt][n][r] * lrow[qt][r]);
      }
}

extern "C" void kernel_launch(void* const* d_in, const int* in_sizes, int n_in,
                              void* d_out, int out_size, void* d_ws, size_t ws_size,
                              hipStream_t stream) {
  (void)in_sizes; (void)n_in; (void)out_size; (void)ws_size;
  const float* x     = (const float*)d_in[0];
  const float* cosb  = (const float*)d_in[1];
  const float* sinb  = (const float*)d_in[2];
  const float* Wqkv  = (const float*)d_in[3];
  const float* wq    = (const float*)d_in[4];
  const float* wk    = (const float*)d_in[5];
  const float* Wproj = (const float*)d_in[6];
  float* out = (float*)d_out;

  char* ws = (char*)d_ws;
  unsigned short* x_bf     = (unsigned short*)(ws);                 // 16 MB
  unsigned short* wqkv_bf  = (unsigned short*)(ws + 16777216);      // 48 MB
  unsigned short* wproj_bf = (unsigned short*)(ws + 67108864);      // 32 MB
  unsigned short* qkv      = (unsigned short*)(ws + 100663296);     // 24 MB (bf16)
  unsigned short* qr       = (unsigned short*)(ws + 150994944);     // 16 MB
  unsigned short* kr       = (unsigned short*)(ws + 167772160);     // 4 MB
  unsigned short* vt       = (unsigned short*)(ws + 171966464);     // 4 MB
  unsigned short* y        = (unsigned short*)(ws + 176160768);     // 16 MB

  cvt_all<<<49152, 256, 0, stream>>>(x, Wqkv, Wproj, x_bf, wqkv_bf, wproj_bf);
  gemm256<<<dim3(32, 8), 512, 0, stream>>>(x_bf, wqkv_bf, qkv, 2048, 6144, 4096);
  normrope<<<2048, 256, 0, stream>>>(qkv, cosb, sinb, wq, wk, qr, kr, vt);
  attn<<<dim3(32, 8), 512, 0, stream>>>(qr, kr, vt, y);
  gemm_bt<float><<<dim3(32, 16), 256, 0, stream>>>(y, wproj_bf, out, 2048, 4096, 4096);
}

// Round 5
// 477.051 us; speedup vs baseline: 1.0558x; 1.0009x over previous
//
#include <hip/hip_runtime.h>
#include <stdint.h>
#include <stddef.h>

#define T_SEQ 2048
#define WINDOW_SZ 1024

typedef __attribute__((ext_vector_type(4))) float f32x4;
typedef __attribute__((ext_vector_type(16))) float f32x16;
typedef __attribute__((ext_vector_type(8))) short s16x8;
typedef __attribute__((ext_vector_type(4))) short s16x4;

__device__ inline unsigned short f2bf(float f) {
  union { float f; unsigned u; } v; v.f = f;
  unsigned u = v.u;
  return (unsigned short)((u + 0x7fffu + ((u >> 16) & 1u)) >> 16);
}
__device__ inline float bf2f(unsigned short u) {
  union { unsigned u; float f; } v; v.u = ((unsigned)u) << 16; return v.f;
}

__device__ inline void gld_lds16(const unsigned short* g, unsigned short* l) {
  __builtin_amdgcn_global_load_lds((const __attribute__((address_space(1))) void*)g,
                                   (__attribute__((address_space(3))) void*)l, 16, 0, 0);
}

__device__ inline void store_out(float* p, float v) { *p = v; }
__device__ inline void store_out(unsigned short* p, float v) { *p = f2bf(v); }

// ---------------- fused fp32 -> bf16 convert for x, W_qkv, W_proj ----------------
__global__ __launch_bounds__(256) void cvt_all(const float* __restrict__ x,
                                               const float* __restrict__ wqkv,
                                               const float* __restrict__ wproj,
                                               unsigned short* __restrict__ x_bf,
                                               unsigned short* __restrict__ wqkv_bf,
                                               unsigned short* __restrict__ wproj_bf) {
  int i = blockIdx.x * 256 + threadIdx.x;  // 0 .. 12582912-1 float4s
  const float* s; unsigned short* d; int j;
  if (i < 2097152)       { s = x;     d = x_bf;     j = i; }
  else if (i < 8388608)  { s = wqkv;  d = wqkv_bf;  j = i - 2097152; }
  else                   { s = wproj; d = wproj_bf; j = i - 8388608; }
  float4 v = ((const float4*)s)[j];
  ushort4 o;
  o.x = f2bf(v.x); o.y = f2bf(v.y); o.z = f2bf(v.z); o.w = f2bf(v.w);
  ((ushort4*)d)[j] = o;
}

// ---------------- 128x128-tile bf16 GEMM (m97-class structure) — used for proj ----------------
template <typename OutT>
__global__ __launch_bounds__(256) void gemm_bt(const unsigned short* __restrict__ A,
                                               const unsigned short* __restrict__ Bt,
                                               OutT* __restrict__ C, int M, int N, int K) {
  __shared__ unsigned short As[128 * 64];  // row r chunk c at r*64+(c^(r&7))*8
  __shared__ unsigned short Bs[128 * 64];
  const int tid  = threadIdx.x;
  const int wave = tid >> 6, lane = tid & 63;
  const int l32 = lane & 31, khalf = lane >> 5;
  const int m0 = blockIdx.y << 7, n0 = blockIdx.x << 7;
  const int wr = (wave >> 1) << 6;
  const int wc = (wave & 1) << 6;
  const int srow = wave * 8 + (lane >> 3);
  const int gchunk0 = lane & 7;

  f32x16 acc[2][2] = {};

  for (int k0 = 0; k0 < K; k0 += 64) {
#pragma unroll
    for (int j = 0; j < 4; j++) {
      int r = j * 32 + srow;
      int gc = gchunk0 ^ (r & 7);
      gld_lds16(A  + (size_t)(m0 + r) * K + k0 + gc * 8, &As[(j * 32 + wave * 8) * 64]);
      gld_lds16(Bt + (size_t)(n0 + r) * K + k0 + gc * 8, &Bs[(j * 32 + wave * 8) * 64]);
    }
    __syncthreads();
#pragma unroll
    for (int s = 0; s < 4; s++) {
      s16x8 af[2], bfr[2];
      int chunk = s * 2 + khalf;
#pragma unroll
      for (int i = 0; i < 2; i++) {
        int ra = wr + i * 32 + l32;
        af[i]  = *(const s16x8*)&As[ra * 64 + ((chunk ^ (ra & 7)) * 8)];
        int rb = wc + i * 32 + l32;
        bfr[i] = *(const s16x8*)&Bs[rb * 64 + ((chunk ^ (rb & 7)) * 8)];
      }
#pragma unroll
      for (int mi = 0; mi < 2; mi++)
#pragma unroll
        for (int ni = 0; ni < 2; ni++)
          acc[mi][ni] = __builtin_amdgcn_mfma_f32_32x32x16_bf16(af[mi], bfr[ni], acc[mi][ni], 0, 0, 0);
    }
    __syncthreads();
  }
#pragma unroll
  for (int mi = 0; mi < 2; mi++)
#pragma unroll
    for (int ni = 0; ni < 2; ni++) {
      int col = n0 + wc + ni * 32 + l32;
      int rbase = m0 + wr + mi * 32 + 4 * khalf;
#pragma unroll
      for (int reg = 0; reg < 16; reg++) {
        int row = rbase + (reg & 3) + 8 * (reg >> 2);
        store_out(&C[(size_t)row * N + col], acc[mi][ni][reg]);
      }
    }
}

// ---------------- 256x192 8-wave single-barrier pipelined GEMM — used for QKV ----------------
// BM=256, BN=192, BK=64 -> grid (32,8) = 256 blocks, exactly 1/CU.
// R5: ONE barrier per K-tile; ds_read <-> MFMA overlap via in-wave fragment pipelining
// (read frag f+2 while MFMA-ing frag f; compiler emits counted lgkmcnt for C++ ds_reads).
// Hazard discipline without inner barriers:
//   A: triple-buffered, staged 2 tiles ahead at top of tile u -> Ab[(u+2)%3] (= buffer whose
//      last reads were in tile u-1, all before the end-of-(u-1) barrier).
//   B: double-buffered, staged 1 tile ahead at top of tile u -> Bb[(u+1)&1] (read buf is Bb[u&1];
//      the target's last reads were in tile u-1).
//   End of tile u: vmcnt(4) keeps exactly A(u+2)'s 4 loads in flight and proves A(u+1)
//   (issued one full tile earlier) and B(u+1) (issued ~2000 cyc earlier) landed; the single
//   barrier then publishes them. Tail (u+2>=NT): vmcnt(0).
__device__ inline void stage_half(const unsigned short* __restrict__ g, int ldk,
                                  int grow0, int k0, unsigned short* lds,
                                  int wave, int lane) {
#pragma unroll
  for (int j = 0; j < 2; j++) {
    int rloc = j * 64 + wave * 8 + (lane >> 3);
    int lc = (lane & 7) ^ (rloc & 7);   // pre-swizzled global source, linear LDS dest
    gld_lds16(g + (size_t)(grow0 + rloc) * ldk + k0 + lc * 8,
              lds + (j * 64 + wave * 8) * 64);
  }
}
__device__ inline void stage_64(const unsigned short* __restrict__ g, int ldk,
                                int grow0, int k0, unsigned short* lds,
                                int wave, int lane) {
  int rloc = wave * 8 + (lane >> 3);
  int lc = (lane & 7) ^ (rloc & 7);
  gld_lds16(g + (size_t)(grow0 + rloc) * ldk + k0 + lc * 8,
            lds + (wave * 8) * 64);
}

__global__ __launch_bounds__(512, 2) void gemm256(const unsigned short* __restrict__ A,
                                                  const unsigned short* __restrict__ Bt,
                                                  unsigned short* __restrict__ C,
                                                  int M, int N, int K) {
  // LDS 136 KiB: A x3 (256x64 = 16384 elems) at i*16384; B x2 (192x64 = 12288) at 49152+b*12288
  __shared__ unsigned short S[73728];
  const int tid = threadIdx.x, wave = tid >> 6, lane = tid & 63;
  const int quad = lane >> 4, l16 = lane & 15;
  const int wm = wave >> 2, wn = wave & 3;          // 2 x 4 wave grid; wave owns 128x48 of C
  const int m0 = blockIdx.y << 8, n0 = blockIdx.x * 192;
  const int NT = K >> 6;

  f32x4 acc[8][3] = {};

  unsigned short* const Ab0 = &S[0];
  unsigned short* const Bb0 = &S[49152];

  // prologue: A0 (4 loads), B0 (3), A1 (4); vmcnt(4) keeps A1 in flight, drains A0+B0.
  stage_half(A,  K, m0,       0, Ab0,        wave, lane);
  stage_half(A,  K, m0 + 128, 0, Ab0 + 8192, wave, lane);
  stage_half(Bt, K, n0,       0, Bb0,        wave, lane);
  stage_64  (Bt, K, n0 + 128, 0, Bb0 + 8192, wave, lane);
  if (NT > 1) {
    stage_half(A,  K, m0,       64, Ab0 + 16384,        wave, lane);
    stage_half(A,  K, m0 + 128, 64, Ab0 + 16384 + 8192, wave, lane);
    asm volatile("s_waitcnt vmcnt(4)" ::: "memory");
  } else {
    asm volatile("s_waitcnt vmcnt(0)" ::: "memory");
  }
  __builtin_amdgcn_s_barrier();
  asm volatile("" ::: "memory");

  int ac = 0;  // A buffer index of tile u (rotates mod 3)
  for (int u = 0; u < NT; ++u) {
    const unsigned short* Sa = Ab0 + ac * 16384;
    const unsigned short* Sb = Bb0 + (u & 1) * 12288;

    // --- stage first: B(u+1) (3 loads), then A(u+2) (4 loads) -> newest 4 in queue = A(u+2)
    if (u + 1 < NT) {
      unsigned short* SbN = Bb0 + ((u + 1) & 1) * 12288;
      stage_half(Bt, K, n0,       (u + 1) << 6, SbN,        wave, lane);
      stage_64  (Bt, K, n0 + 128, (u + 1) << 6, SbN + 8192, wave, lane);
    }
    if (u + 2 < NT) {
      int an2 = ac - 1; if (an2 < 0) an2 = 2;               // (ac+2)%3
      unsigned short* SaN = Ab0 + an2 * 16384;
      stage_half(A, K, m0,       (u + 2) << 6, SaN,        wave, lane);
      stage_half(A, K, m0 + 128, (u + 2) << 6, SaN + 8192, wave, lane);
    }

    // --- fragment-pipelined compute: read frag f+2 while MFMA-ing frag f ---
    s16x8 bfr[3][2];
#pragma unroll
    for (int nf = 0; nf < 3; nf++)
#pragma unroll
      for (int ks = 0; ks < 2; ks++) {
        int rb = wn * 48 + nf * 16 + l16;
        bfr[nf][ks] = *(const s16x8*)&Sb[rb * 64 + (((ks * 4 + quad) ^ (rb & 7)) * 8)];
      }
    s16x8 af[8][2];
#pragma unroll
    for (int f = 0; f < 2; f++)
#pragma unroll
      for (int ks = 0; ks < 2; ks++) {
        int ra = wm * 128 + f * 16 + l16;
        af[f][ks] = *(const s16x8*)&Sa[ra * 64 + (((ks * 4 + quad) ^ (ra & 7)) * 8)];
      }
#pragma unroll
    for (int f = 0; f < 8; f++) {
      if (f < 6) {
#pragma unroll
        for (int ks = 0; ks < 2; ks++) {
          int ra = wm * 128 + (f + 2) * 16 + l16;
          af[f + 2][ks] = *(const s16x8*)&Sa[ra * 64 + (((ks * 4 + quad) ^ (ra & 7)) * 8)];
        }
      }
      __builtin_amdgcn_s_setprio(1);
#pragma unroll
      for (int nf = 0; nf < 3; nf++)
#pragma unroll
        for (int ks = 0; ks < 2; ks++)
          acc[f][nf] = __builtin_amdgcn_mfma_f32_16x16x32_bf16(
              af[f][ks], bfr[nf][ks], acc[f][nf], 0, 0, 0);
      __builtin_amdgcn_s_setprio(0);
    }

    // --- end of tile: counted drain + single publishing barrier ---
    if (u + 2 < NT) asm volatile("s_waitcnt vmcnt(4)" ::: "memory");
    else            asm volatile("s_waitcnt vmcnt(0)" ::: "memory");
    asm volatile("" ::: "memory");
    __builtin_amdgcn_s_barrier();
    asm volatile("" ::: "memory");

    ac = (ac == 2) ? 0 : ac + 1;
  }
  // C/D 16x16: col = lane&15, row = quad*4 + reg  [m89]
#pragma unroll
  for (int mf = 0; mf < 8; mf++)
#pragma unroll
    for (int nf = 0; nf < 3; nf++) {
      const int row0 = m0 + wm * 128 + mf * 16 + quad * 4;
      const int col  = n0 + wn * 48 + nf * 16 + l16;
#pragma unroll
      for (int r = 0; r < 4; r++)
        C[(size_t)(row0 + r) * N + col] = f2bf(acc[mf][nf][r]);
    }
}

// ---------------- fused RMSNorm + RoPE + layout (one block per token) ----------------
__global__ __launch_bounds__(256) void normrope(const unsigned short* __restrict__ qkv,
                                                const float* __restrict__ cosb,
                                                const float* __restrict__ sinb,
                                                const float* __restrict__ wq,
                                                const float* __restrict__ wk,
                                                unsigned short* __restrict__ qr,
                                                unsigned short* __restrict__ kr,
                                                unsigned short* __restrict__ vt) {
  const int t = blockIdx.x, tid = threadIdx.x;
  const unsigned short* row = qkv + (size_t)t * 6144;
  float sq = 0.f, sk = 0.f;
  {
    s16x8 a = *(const s16x8*)&row[tid * 16];
    s16x8 b = *(const s16x8*)&row[tid * 16 + 8];
#pragma unroll
    for (int j = 0; j < 8; j++) {
      float fa = bf2f((unsigned short)a[j]), fb = bf2f((unsigned short)b[j]);
      sq += fa * fa + fb * fb;
    }
  }
  {
    s16x4 a = *(const s16x4*)&row[4096 + tid * 4];
#pragma unroll
    for (int j = 0; j < 4; j++) {
      float fa = bf2f((unsigned short)a[j]);
      sk += fa * fa;
    }
  }
#pragma unroll
  for (int off = 32; off; off >>= 1) { sq += __shfl_xor(sq, off); sk += __shfl_xor(sk, off); }
  __shared__ float red[8];
  if ((tid & 63) == 0) { red[tid >> 6] = sq; red[4 + (tid >> 6)] = sk; }
  __syncthreads();
  sq = red[0] + red[1] + red[2] + red[3];
  sk = red[4] + red[5] + red[6] + red[7];
  const float rq = rsqrtf(sq * (1.f / 4096.f) + 1e-5f) * (0.08838834764831845f * 1.4426950408889634f);
  const float rk = rsqrtf(sk * (1.f / 1024.f) + 1e-5f);
  for (int i = tid; i < 4096; i += 256) {
    int h = i >> 7, d = i & 127;
    int pd = (d < 64) ? d + 64 : d - 64;
    float val = bf2f(row[i]) * rq * wq[i];
    float pv  = bf2f(row[(h << 7) + pd]) * rq * wq[(h << 7) + pd];
    float rot = (d < 64) ? -pv : pv;
    float o = val * cosb[t * 128 + d] + rot * sinb[t * 128 + d];
    qr[(size_t)h * T_SEQ * 128 + t * 128 + d] = f2bf(o);
  }
  for (int i = tid; i < 1024; i += 256) {
    int g = i >> 7, d = i & 127;
    int pd = (d < 64) ? d + 64 : d - 64;
    float val = bf2f(row[4096 + i]) * rk * wk[i];
    float pv  = bf2f(row[4096 + (g << 7) + pd]) * rk * wk[(g << 7) + pd];
    float rot = (d < 64) ? -pv : pv;
    float o = val * cosb[t * 128 + d] + rot * sinb[t * 128 + d];
    kr[(size_t)g * T_SEQ * 128 + t * 128 + d] = f2bf(o);
  }
  for (int i = tid; i < 1024; i += 256) {
    int g = i >> 7, d = i & 127;
    vt[(size_t)g * 128 * T_SEQ + (size_t)d * T_SEQ + t] = row[5120 + i];
  }
}

// ---------------- flash attention, sliding window, block-shared LDS K/V ----------------
__global__ __launch_bounds__(512, 2) void attn(const unsigned short* __restrict__ Q,
                                               const unsigned short* __restrict__ Kb,
                                               const unsigned short* __restrict__ Vt,
                                               unsigned short* __restrict__ Y) {
  __shared__ unsigned short Kbuf[2][64 * 128];
  __shared__ unsigned short Vbuf[2][128 * 64];
  __shared__ unsigned short Pbuf[8][2][16 * 72];
  const int qb = blockIdx.x, g = blockIdx.y;
  const int tid = threadIdx.x, wave = tid >> 6, lane = tid & 63;
  const int quad = lane >> 4, l16 = lane & 15;
  const int h = g * 4 + (wave >> 1);
  const int qbase = qb * 64;
  const int q0 = qbase + (wave & 1) * 32;
  const unsigned short* Qh = Q + (size_t)h * T_SEQ * 128;
  const unsigned short* Kg = Kb + (size_t)g * T_SEQ * 128;
  const unsigned short* Vg = Vt + (size_t)g * 128 * T_SEQ;

  s16x8 aq[2][4];
#pragma unroll
  for (int qt = 0; qt < 2; qt++)
#pragma unroll
    for (int ks = 0; ks < 4; ks++)
      aq[qt][ks] = *(const s16x8*)&Qh[(size_t)(q0 + qt * 16 + l16) * 128 + ks * 32 + quad * 8];

  f32x4 acc[2][8] = {};
  float lrow[2][4] = {};

  int lo = qbase - (WINDOW_SZ - 1);
  if (lo < 0) lo = 0;
  lo &= ~63;

#define STAGE_CHUNK(buf, kkv)                                                        \
  {                                                                                  \
    int kk_ = (kkv);                                                                 \
    _Pragma("unroll")                                                                \
    for (int j = 0; j < 2; j++) {                                                    \
      int rloc = wave * 8 + j * 4 + (lane >> 4);                                     \
      int oct = (lane & 15) ^ (rloc & 15);                                           \
      gld_lds16(Kg + (size_t)(kk_ + rloc) * 128 + oct * 8,                           \
                &Kbuf[buf][(wave * 8 + j * 4) * 128]);                               \
    }                                                                                \
    _Pragma("unroll")                                                                \
    for (int j = 0; j < 2; j++) {                                                    \
      int dloc = wave * 16 + j * 8 + (lane >> 3);                                    \
      int oct = (lane & 7) ^ (dloc & 7);                                             \
      gld_lds16(Vg + (size_t)dloc * T_SEQ + kk_ + oct * 8,                           \
                &Vbuf[buf][(wave * 16 + j * 8) * 64]);                               \
    }                                                                                \
  }

  STAGE_CHUNK(0, lo);
  int ib = 0;
  for (int kk = lo; kk < qbase + 64; kk += 64, ib ^= 1) {
    __syncthreads();
    if (kk + 64 < qbase + 64) STAGE_CHUNK(ib ^ 1, kk + 64);
    if (kk > q0 + 31 || kk + 63 < q0 - (WINDOW_SZ - 1)) continue;
    const unsigned short* kb = Kbuf[ib];
    const unsigned short* vb = Vbuf[ib];
    f32x4 sc[2][4] = {};
    __builtin_amdgcn_s_setprio(1);
#pragma unroll
    for (int ks = 0; ks < 4; ks++) {
#pragma unroll
      for (int ci = 0; ci < 4; ci++) {
        s16x8 bk = *(const s16x8*)&kb[(ci * 16 + l16) * 128 + (((ks * 4 + quad) ^ l16) * 8)];
        sc[0][ci] = __builtin_amdgcn_mfma_f32_16x16x32_bf16(aq[0][ks], bk, sc[0][ci], 0, 0, 0);
        sc[1][ci] = __builtin_amdgcn_mfma_f32_16x16x32_bf16(aq[1][ks], bk, sc[1][ci], 0, 0, 0);
      }
    }
    __builtin_amdgcn_s_setprio(0);
#pragma unroll
    for (int qt = 0; qt < 2; qt++)
#pragma unroll
      for (int ci = 0; ci < 4; ci++) {
        int col = kk + ci * 16 + l16;
#pragma unroll
        for (int r = 0; r < 4; r++) {
          int irow = q0 + qt * 16 + quad * 4 + r;
          unsigned dd = (unsigned)(irow - col);
          float e = (dd < (unsigned)WINDOW_SZ) ? exp2f(sc[qt][ci][r]) : 0.f;
          lrow[qt][r] += e;
          Pbuf[wave][qt][(quad * 4 + r) * 72 + ci * 16 + l16] = f2bf(e);
        }
      }
    __builtin_amdgcn_s_setprio(1);
#pragma unroll
    for (int c = 0; c < 2; c++) {
      s16x8 pa0 = *(const s16x8*)&Pbuf[wave][0][l16 * 72 + c * 32 + quad * 8];
      s16x8 pa1 = *(const s16x8*)&Pbuf[wave][1][l16 * 72 + c * 32 + quad * 8];
#pragma unroll
      for (int n = 0; n < 8; n++) {
        s16x8 bv = *(const s16x8*)&vb[(n * 16 + l16) * 64 + (((c * 4 + quad) ^ (l16 & 7)) * 8)];
        acc[0][n] = __builtin_amdgcn_mfma_f32_16x16x32_bf16(pa0, bv, acc[0][n], 0, 0, 0);
        acc[1][n] = __builtin_amdgcn_mfma_f32_16x16x32_bf16(pa1, bv, acc[1][n], 0, 0, 0);
      }
    }
    __builtin_amdgcn_s_setprio(0);
  }
#undef STAGE_CHUNK
#pragma unroll
  for (int qt = 0; qt < 2; qt++)
#pragma unroll
    for (int r = 0; r < 4; r++) {
#pragma unroll
      for (int off = 8; off; off >>= 1) lrow[qt][r] += __shfl_xor(lrow[qt][r], off);
      lrow[qt][r] = 1.f / lrow[qt][r];
    }
#pragma unroll
  for (int qt = 0; qt < 2; qt++)
#pragma unroll
    for (int n = 0; n < 8; n++)
#pragma unroll
      for (int r = 0; r < 4; r++) {
        int irow = q0 + qt * 16 + quad * 4 + r;
        Y[(size_t)irow * 4096 + h * 128 + n * 16 + l16] = f2bf(acc[qt][n][r] * lrow[qt][r]);
      }
}

extern "C" void kernel_launch(void* const* d_in, const int* in_sizes, int n_in,
                              void* d_out, int out_size, void* d_ws, size_t ws_size,
                              hipStream_t stream) {
  (void)in_sizes; (void)n_in; (void)out_size; (void)ws_size;
  const float* x     = (const float*)d_in[0];
  const float* cosb  = (const float*)d_in[1];
  const float* sinb  = (const float*)d_in[2];
  const float* Wqkv  = (const float*)d_in[3];
  const float* wq    = (const float*)d_in[4];
  const float* wk    = (const float*)d_in[5];
  const float* Wproj = (const float*)d_in[6];
  float* out = (float*)d_out;

  char* ws = (char*)d_ws;
  unsigned short* x_bf     = (unsigned short*)(ws);                 // 16 MB
  unsigned short* wqkv_bf  = (unsigned short*)(ws + 16777216);      // 48 MB
  unsigned short* wproj_bf = (unsigned short*)(ws + 67108864);      // 32 MB
  unsigned short* qkv      = (unsigned short*)(ws + 100663296);     // 24 MB (bf16)
  unsigned short* qr       = (unsigned short*)(ws + 150994944);     // 16 MB
  unsigned short* kr       = (unsigned short*)(ws + 167772160);     // 4 MB
  unsigned short* vt       = (unsigned short*)(ws + 171966464);     // 4 MB
  unsigned short* y        = (unsigned short*)(ws + 176160768);     // 16 MB

  cvt_all<<<49152, 256, 0, stream>>>(x, Wqkv, Wproj, x_bf, wqkv_bf, wproj_bf);
  gemm256<<<dim3(32, 8), 512, 0, stream>>>(x_bf, wqkv_bf, qkv, 2048, 6144, 4096);
  normrope<<<2048, 256, 0, stream>>>(qkv, cosb, sinb, wq, wk, qr, kr, vt);
  attn<<<dim3(32, 8), 512, 0, stream>>>(qr, kr, vt, y);
  gemm_bt<float><<<dim3(32, 16), 256, 0, stream>>>(y, wproj_bf, out, 2048, 4096, 4096);
}

// Round 7
// 463.060 us; speedup vs baseline: 1.0877x; 1.0302x over previous
//
#include <hip/hip_runtime.h>
#include <stdint.h>
#include <stddef.h>

#define T_SEQ 2048
#define WINDOW_SZ 1024

typedef __attribute__((ext_vector_type(4))) float f32x4;
typedef __attribute__((ext_vector_type(16))) float f32x16;
typedef __attribute__((ext_vector_type(8))) short s16x8;
typedef __attribute__((ext_vector_type(4))) short s16x4;

__device__ inline unsigned short f2bf(float f) {
  union { float f; unsigned u; } v; v.f = f;
  unsigned u = v.u;
  return (unsigned short)((u + 0x7fffu + ((u >> 16) & 1u)) >> 16);
}
__device__ inline float bf2f(unsigned short u) {
  union { unsigned u; float f; } v; v.u = ((unsigned)u) << 16; return v.f;
}

__device__ inline void gld_lds16(const unsigned short* g, unsigned short* l) {
  __builtin_amdgcn_global_load_lds((const __attribute__((address_space(1))) void*)g,
                                   (__attribute__((address_space(3))) void*)l, 16, 0, 0);
}

// ---------------- fused fp32 -> bf16 convert for x, W_qkv, W_proj ----------------
__global__ __launch_bounds__(256) void cvt_all(const float* __restrict__ x,
                                               const float* __restrict__ wqkv,
                                               const float* __restrict__ wproj,
                                               unsigned short* __restrict__ x_bf,
                                               unsigned short* __restrict__ wqkv_bf,
                                               unsigned short* __restrict__ wproj_bf) {
  int i = blockIdx.x * 256 + threadIdx.x;  // 0 .. 12582912-1 float4s
  const float* s; unsigned short* d; int j;
  if (i < 2097152)       { s = x;     d = x_bf;     j = i; }
  else if (i < 8388608)  { s = wqkv;  d = wqkv_bf;  j = i - 2097152; }
  else                   { s = wproj; d = wproj_bf; j = i - 8388608; }
  float4 v = ((const float4*)s)[j];
  ushort4 o;
  o.x = f2bf(v.x); o.y = f2bf(v.y); o.z = f2bf(v.z); o.w = f2bf(v.w);
  ((ushort4*)d)[j] = o;
}

// ---------------- staging helpers (pre-swizzled global source, linear LDS dest) ----------------
__device__ inline void stage_half(const unsigned short* __restrict__ g, int ldk,
                                  int grow0, int k0, unsigned short* lds,
                                  int wave, int lane) {
#pragma unroll
  for (int j = 0; j < 2; j++) {
    int rloc = j * 64 + wave * 8 + (lane >> 3);
    int lc = (lane & 7) ^ (rloc & 7);
    gld_lds16(g + (size_t)(grow0 + rloc) * ldk + k0 + lc * 8,
              lds + (j * 64 + wave * 8) * 64);
  }
}
__device__ inline void stage_64(const unsigned short* __restrict__ g, int ldk,
                                int grow0, int k0, unsigned short* lds,
                                int wave, int lane) {
  int rloc = wave * 8 + (lane >> 3);
  int lc = (lane & 7) ^ (rloc & 7);
  gld_lds16(g + (size_t)(grow0 + rloc) * ldk + k0 + lc * 8,
            lds + (wave * 8) * 64);
}

// ---------------- 256x192 8-wave single-barrier pipelined GEMM — QKV (R5, unchanged) ----------------
__global__ __launch_bounds__(512, 2) void gemm256(const unsigned short* __restrict__ A,
                                                  const unsigned short* __restrict__ Bt,
                                                  unsigned short* __restrict__ C,
                                                  int M, int N, int K) {
  __shared__ unsigned short S[73728];
  const int tid = threadIdx.x, wave = tid >> 6, lane = tid & 63;
  const int quad = lane >> 4, l16 = lane & 15;
  const int wm = wave >> 2, wn = wave & 3;          // wave owns 128x48 of C
  const int m0 = blockIdx.y << 8, n0 = blockIdx.x * 192;
  const int NT = K >> 6;

  f32x4 acc[8][3] = {};

  unsigned short* const Ab0 = &S[0];
  unsigned short* const Bb0 = &S[49152];

  stage_half(A,  K, m0,       0, Ab0,        wave, lane);
  stage_half(A,  K, m0 + 128, 0, Ab0 + 8192, wave, lane);
  stage_half(Bt, K, n0,       0, Bb0,        wave, lane);
  stage_64  (Bt, K, n0 + 128, 0, Bb0 + 8192, wave, lane);
  if (NT > 1) {
    stage_half(A,  K, m0,       64, Ab0 + 16384,        wave, lane);
    stage_half(A,  K, m0 + 128, 64, Ab0 + 16384 + 8192, wave, lane);
    asm volatile("s_waitcnt vmcnt(4)" ::: "memory");
  } else {
    asm volatile("s_waitcnt vmcnt(0)" ::: "memory");
  }
  __builtin_amdgcn_s_barrier();
  asm volatile("" ::: "memory");

  int ac = 0;
  for (int u = 0; u < NT; ++u) {
    const unsigned short* Sa = Ab0 + ac * 16384;
    const unsigned short* Sb = Bb0 + (u & 1) * 12288;

    if (u + 1 < NT) {
      unsigned short* SbN = Bb0 + ((u + 1) & 1) * 12288;
      stage_half(Bt, K, n0,       (u + 1) << 6, SbN,        wave, lane);
      stage_64  (Bt, K, n0 + 128, (u + 1) << 6, SbN + 8192, wave, lane);
    }
    if (u + 2 < NT) {
      int an2 = ac - 1; if (an2 < 0) an2 = 2;
      unsigned short* SaN = Ab0 + an2 * 16384;
      stage_half(A, K, m0,       (u + 2) << 6, SaN,        wave, lane);
      stage_half(A, K, m0 + 128, (u + 2) << 6, SaN + 8192, wave, lane);
    }

    s16x8 bfr[3][2];
#pragma unroll
    for (int nf = 0; nf < 3; nf++)
#pragma unroll
      for (int ks = 0; ks < 2; ks++) {
        int rb = wn * 48 + nf * 16 + l16;
        bfr[nf][ks] = *(const s16x8*)&Sb[rb * 64 + (((ks * 4 + quad) ^ (rb & 7)) * 8)];
      }
    s16x8 af[8][2];
#pragma unroll
    for (int f = 0; f < 2; f++)
#pragma unroll
      for (int ks = 0; ks < 2; ks++) {
        int ra = wm * 128 + f * 16 + l16;
        af[f][ks] = *(const s16x8*)&Sa[ra * 64 + (((ks * 4 + quad) ^ (ra & 7)) * 8)];
      }
#pragma unroll
    for (int f = 0; f < 8; f++) {
      if (f < 6) {
#pragma unroll
        for (int ks = 0; ks < 2; ks++) {
          int ra = wm * 128 + (f + 2) * 16 + l16;
          af[f + 2][ks] = *(const s16x8*)&Sa[ra * 64 + (((ks * 4 + quad) ^ (ra & 7)) * 8)];
        }
      }
      __builtin_amdgcn_s_setprio(1);
#pragma unroll
      for (int nf = 0; nf < 3; nf++)
#pragma unroll
        for (int ks = 0; ks < 2; ks++)
          acc[f][nf] = __builtin_amdgcn_mfma_f32_16x16x32_bf16(
              af[f][ks], bfr[nf][ks], acc[f][nf], 0, 0, 0);
      __builtin_amdgcn_s_setprio(0);
    }

    if (u + 2 < NT) asm volatile("s_waitcnt vmcnt(4)" ::: "memory");
    else            asm volatile("s_waitcnt vmcnt(0)" ::: "memory");
    asm volatile("" ::: "memory");
    __builtin_amdgcn_s_barrier();
    asm volatile("" ::: "memory");

    ac = (ac == 2) ? 0 : ac + 1;
  }
#pragma unroll
  for (int mf = 0; mf < 8; mf++)
#pragma unroll
    for (int nf = 0; nf < 3; nf++) {
      const int row0 = m0 + wm * 128 + mf * 16 + quad * 4;
      const int col  = n0 + wn * 48 + nf * 16 + l16;
#pragma unroll
      for (int r = 0; r < 4; r++)
        C[(size_t)(row0 + r) * N + col] = f2bf(acc[mf][nf][r]);
    }
}

// ---------------- 128x256 8-wave single-barrier pipelined GEMM, fp32 out — proj ----------------
// BM=128, BN=256, BK=64 -> grid (4096/256, 2048/128) = (16,16) = 256 blocks, 1/CU.
// Mirror of gemm256's proven schedule with roles swapped:
//   B (big operand) triple-buffered, staged 2 tiles ahead -> Bb[(u+2)%3]
//   A double-buffered, staged 1 tile ahead -> Ab[(u+1)&1]
//   In-loop issue order: A(u+1) (2 loads) THEN B(u+2) (4 loads); end-of-tile vmcnt(4)
//   keeps exactly B(u+2) in flight, proves A(u+1) and B(u+1) (issued one tile earlier).
//   Tail (u+2>=NT): vmcnt(0). Prologue: A0,B0 then B1; vmcnt(4) proves A0+B0.
// Wave tile 64x64 = 4x4 16x16-frags; reads use l16 rows (conflict-free XOR pattern).
__global__ __launch_bounds__(512, 2) void gemm256p(const unsigned short* __restrict__ A,
                                                   const unsigned short* __restrict__ Bt,
                                                   float* __restrict__ C,
                                                   int M, int N, int K) {
  // LDS 128 KiB: B x3 (256x64 = 16384 elems) at i*16384; A x2 (128x64 = 8192) at 49152 + a*8192
  __shared__ unsigned short S[65536];
  const int tid = threadIdx.x, wave = tid >> 6, lane = tid & 63;
  const int quad = lane >> 4, l16 = lane & 15;
  const int wm = wave >> 2, wn = wave & 3;          // 2 x 4 wave grid; wave owns 64x64 of C
  const int m0 = blockIdx.y << 7, n0 = blockIdx.x << 8;
  const int NT = K >> 6;

  f32x4 acc[4][4] = {};

  unsigned short* const Bb0 = &S[0];
  unsigned short* const Ab0 = &S[49152];

  // prologue: A0 (2 loads), B0 (4), B1 (4); vmcnt(4) keeps B1 in flight, proves A0+B0
  stage_half(A,  K, m0,       0, Ab0,        wave, lane);
  stage_half(Bt, K, n0,       0, Bb0,        wave, lane);
  stage_half(Bt, K, n0 + 128, 0, Bb0 + 8192, wave, lane);
  if (NT > 1) {
    stage_half(Bt, K, n0,       64, Bb0 + 16384,        wave, lane);
    stage_half(Bt, K, n0 + 128, 64, Bb0 + 16384 + 8192, wave, lane);
    asm volatile("s_waitcnt vmcnt(4)" ::: "memory");
  } else {
    asm volatile("s_waitcnt vmcnt(0)" ::: "memory");
  }
  __builtin_amdgcn_s_barrier();
  asm volatile("" ::: "memory");

  int bc = 0;  // B buffer index of tile u (rotates mod 3)
  for (int u = 0; u < NT; ++u) {
    const unsigned short* Sb = Bb0 + bc * 16384;
    const unsigned short* Sa = Ab0 + (u & 1) * 8192;

    // stage A(u+1) first, then B(u+2): newest 4 in queue = B(u+2)
    if (u + 1 < NT)
      stage_half(A, K, m0, (u + 1) << 6, Ab0 + ((u + 1) & 1) * 8192, wave, lane);
    if (u + 2 < NT) {
      int bn2 = bc - 1; if (bn2 < 0) bn2 = 2;               // (bc+2)%3
      unsigned short* SbN = Bb0 + bn2 * 16384;
      stage_half(Bt, K, n0,       (u + 2) << 6, SbN,        wave, lane);
      stage_half(Bt, K, n0 + 128, (u + 2) << 6, SbN + 8192, wave, lane);
    }

    // fragment-pipelined compute: read af[mf+1] while MFMA-ing mf
    s16x8 bfr[4][2];
#pragma unroll
    for (int nf = 0; nf < 4; nf++)
#pragma unroll
      for (int ks = 0; ks < 2; ks++) {
        int rb = wn * 64 + nf * 16 + l16;
        bfr[nf][ks] = *(const s16x8*)&Sb[rb * 64 + (((ks * 4 + quad) ^ (rb & 7)) * 8)];
      }
    s16x8 af[4][2];
#pragma unroll
    for (int ks = 0; ks < 2; ks++) {
      int ra = wm * 64 + l16;
      af[0][ks] = *(const s16x8*)&Sa[ra * 64 + (((ks * 4 + quad) ^ (ra & 7)) * 8)];
    }
#pragma unroll
    for (int mf = 0; mf < 4; mf++) {
      if (mf < 3) {
#pragma unroll
        for (int ks = 0; ks < 2; ks++) {
          int ra = wm * 64 + (mf + 1) * 16 + l16;
          af[mf + 1][ks] = *(const s16x8*)&Sa[ra * 64 + (((ks * 4 + quad) ^ (ra & 7)) * 8)];
        }
      }
      __builtin_amdgcn_s_setprio(1);
#pragma unroll
      for (int nf = 0; nf < 4; nf++)
#pragma unroll
        for (int ks = 0; ks < 2; ks++)
          acc[mf][nf] = __builtin_amdgcn_mfma_f32_16x16x32_bf16(
              af[mf][ks], bfr[nf][ks], acc[mf][nf], 0, 0, 0);
      __builtin_amdgcn_s_setprio(0);
    }

    if (u + 2 < NT) asm volatile("s_waitcnt vmcnt(4)" ::: "memory");
    else            asm volatile("s_waitcnt vmcnt(0)" ::: "memory");
    asm volatile("" ::: "memory");
    __builtin_amdgcn_s_barrier();
    asm volatile("" ::: "memory");

    bc = (bc == 2) ? 0 : bc + 1;
  }
  // C/D 16x16: col = lane&15, row = quad*4 + reg  [m89]
#pragma unroll
  for (int mf = 0; mf < 4; mf++)
#pragma unroll
    for (int nf = 0; nf < 4; nf++) {
      const int row0 = m0 + wm * 64 + mf * 16 + quad * 4;
      const int col  = n0 + wn * 64 + nf * 16 + l16;
#pragma unroll
      for (int r = 0; r < 4; r++)
        C[(size_t)(row0 + r) * N + col] = acc[mf][nf][r];
    }
}

// ---------------- fused RMSNorm + RoPE + layout (one block per token) ----------------
__global__ __launch_bounds__(256) void normrope(const unsigned short* __restrict__ qkv,
                                                const float* __restrict__ cosb,
                                                const float* __restrict__ sinb,
                                                const float* __restrict__ wq,
                                                const float* __restrict__ wk,
                                                unsigned short* __restrict__ qr,
                                                unsigned short* __restrict__ kr,
                                                unsigned short* __restrict__ vt) {
  const int t = blockIdx.x, tid = threadIdx.x;
  const unsigned short* row = qkv + (size_t)t * 6144;
  float sq = 0.f, sk = 0.f;
  {
    s16x8 a = *(const s16x8*)&row[tid * 16];
    s16x8 b = *(const s16x8*)&row[tid * 16 + 8];
#pragma unroll
    for (int j = 0; j < 8; j++) {
      float fa = bf2f((unsigned short)a[j]), fb = bf2f((unsigned short)b[j]);
      sq += fa * fa + fb * fb;
    }
  }
  {
    s16x4 a = *(const s16x4*)&row[4096 + tid * 4];
#pragma unroll
    for (int j = 0; j < 4; j++) {
      float fa = bf2f((unsigned short)a[j]);
      sk += fa * fa;
    }
  }
#pragma unroll
  for (int off = 32; off; off >>= 1) { sq += __shfl_xor(sq, off); sk += __shfl_xor(sk, off); }
  __shared__ float red[8];
  if ((tid & 63) == 0) { red[tid >> 6] = sq; red[4 + (tid >> 6)] = sk; }
  __syncthreads();
  sq = red[0] + red[1] + red[2] + red[3];
  sk = red[4] + red[5] + red[6] + red[7];
  const float rq = rsqrtf(sq * (1.f / 4096.f) + 1e-5f) * (0.08838834764831845f * 1.4426950408889634f);
  const float rk = rsqrtf(sk * (1.f / 1024.f) + 1e-5f);
  for (int i = tid; i < 4096; i += 256) {
    int h = i >> 7, d = i & 127;
    int pd = (d < 64) ? d + 64 : d - 64;
    float val = bf2f(row[i]) * rq * wq[i];
    float pv  = bf2f(row[(h << 7) + pd]) * rq * wq[(h << 7) + pd];
    float rot = (d < 64) ? -pv : pv;
    float o = val * cosb[t * 128 + d] + rot * sinb[t * 128 + d];
    qr[(size_t)h * T_SEQ * 128 + t * 128 + d] = f2bf(o);
  }
  for (int i = tid; i < 1024; i += 256) {
    int g = i >> 7, d = i & 127;
    int pd = (d < 64) ? d + 64 : d - 64;
    float val = bf2f(row[4096 + i]) * rk * wk[i];
    float pv  = bf2f(row[4096 + (g << 7) + pd]) * rk * wk[(g << 7) + pd];
    float rot = (d < 64) ? -pv : pv;
    float o = val * cosb[t * 128 + d] + rot * sinb[t * 128 + d];
    kr[(size_t)g * T_SEQ * 128 + t * 128 + d] = f2bf(o);
  }
  for (int i = tid; i < 1024; i += 256) {
    int g = i >> 7, d = i & 127;
    vt[(size_t)g * 128 * T_SEQ + (size_t)d * T_SEQ + t] = row[5120 + i];
  }
}

// ---------------- flash attention, sliding window, block-shared LDS K/V ----------------
__global__ __launch_bounds__(512, 2) void attn(const unsigned short* __restrict__ Q,
                                               const unsigned short* __restrict__ Kb,
                                               const unsigned short* __restrict__ Vt,
                                               unsigned short* __restrict__ Y) {
  __shared__ unsigned short Kbuf[2][64 * 128];
  __shared__ unsigned short Vbuf[2][128 * 64];
  __shared__ unsigned short Pbuf[8][2][16 * 72];
  const int qb = blockIdx.x, g = blockIdx.y;
  const int tid = threadIdx.x, wave = tid >> 6, lane = tid & 63;
  const int quad = lane >> 4, l16 = lane & 15;
  const int h = g * 4 + (wave >> 1);
  const int qbase = qb * 64;
  const int q0 = qbase + (wave & 1) * 32;
  const unsigned short* Qh = Q + (size_t)h * T_SEQ * 128;
  const unsigned short* Kg = Kb + (size_t)g * T_SEQ * 128;
  const unsigned short* Vg = Vt + (size_t)g * 128 * T_SEQ;

  s16x8 aq[2][4];
#pragma unroll
  for (int qt = 0; qt < 2; qt++)
#pragma unroll
    for (int ks = 0; ks < 4; ks++)
      aq[qt][ks] = *(const s16x8*)&Qh[(size_t)(q0 + qt * 16 + l16) * 128 + ks * 32 + quad * 8];

  f32x4 acc[2][8] = {};
  float lrow[2][4] = {};

  int lo = qbase - (WINDOW_SZ - 1);
  if (lo < 0) lo = 0;
  lo &= ~63;

#define STAGE_CHUNK(buf, kkv)                                                        \
  {                                                                                  \
    int kk_ = (kkv);                                                                 \
    _Pragma("unroll")                                                                \
    for (int j = 0; j < 2; j++) {                                                    \
      int rloc = wave * 8 + j * 4 + (lane >> 4);                                     \
      int oct = (lane & 15) ^ (rloc & 15);                                           \
      gld_lds16(Kg + (size_t)(kk_ + rloc) * 128 + oct * 8,                           \
                &Kbuf[buf][(wave * 8 + j * 4) * 128]);                               \
    }                                                                                \
    _Pragma("unroll")                                                                \
    for (int j = 0; j < 2; j++) {                                                    \
      int dloc = wave * 16 + j * 8 + (lane >> 3);                                    \
      int oct = (lane & 7) ^ (dloc & 7);                                             \
      gld_lds16(Vg + (size_t)dloc * T_SEQ + kk_ + oct * 8,                           \
                &Vbuf[buf][(wave * 16 + j * 8) * 64]);                               \
    }                                                                                \
  }

  STAGE_CHUNK(0, lo);
  int ib = 0;
  for (int kk = lo; kk < qbase + 64; kk += 64, ib ^= 1) {
    __syncthreads();
    if (kk + 64 < qbase + 64) STAGE_CHUNK(ib ^ 1, kk + 64);
    if (kk > q0 + 31 || kk + 63 < q0 - (WINDOW_SZ - 1)) continue;
    const unsigned short* kb = Kbuf[ib];
    const unsigned short* vb = Vbuf[ib];
    f32x4 sc[2][4] = {};
    __builtin_amdgcn_s_setprio(1);
#pragma unroll
    for (int ks = 0; ks < 4; ks++) {
#pragma unroll
      for (int ci = 0; ci < 4; ci++) {
        s16x8 bk = *(const s16x8*)&kb[(ci * 16 + l16) * 128 + (((ks * 4 + quad) ^ l16) * 8)];
        sc[0][ci] = __builtin_amdgcn_mfma_f32_16x16x32_bf16(aq[0][ks], bk, sc[0][ci], 0, 0, 0);
        sc[1][ci] = __builtin_amdgcn_mfma_f32_16x16x32_bf16(aq[1][ks], bk, sc[1][ci], 0, 0, 0);
      }
    }
    __builtin_amdgcn_s_setprio(0);
#pragma unroll
    for (int qt = 0; qt < 2; qt++)
#pragma unroll
      for (int ci = 0; ci < 4; ci++) {
        int col = kk + ci * 16 + l16;
#pragma unroll
        for (int r = 0; r < 4; r++) {
          int irow = q0 + qt * 16 + quad * 4 + r;
          unsigned dd = (unsigned)(irow - col);
          float e = (dd < (unsigned)WINDOW_SZ) ? exp2f(sc[qt][ci][r]) : 0.f;
          lrow[qt][r] += e;
          Pbuf[wave][qt][(quad * 4 + r) * 72 + ci * 16 + l16] = f2bf(e);
        }
      }
    __builtin_amdgcn_s_setprio(1);
#pragma unroll
    for (int c = 0; c < 2; c++) {
      s16x8 pa0 = *(const s16x8*)&Pbuf[wave][0][l16 * 72 + c * 32 + quad * 8];
      s16x8 pa1 = *(const s16x8*)&Pbuf[wave][1][l16 * 72 + c * 32 + quad * 8];
#pragma unroll
      for (int n = 0; n < 8; n++) {
        s16x8 bv = *(const s16x8*)&vb[(n * 16 + l16) * 64 + (((c * 4 + quad) ^ (l16 & 7)) * 8)];
        acc[0][n] = __builtin_amdgcn_mfma_f32_16x16x32_bf16(pa0, bv, acc[0][n], 0, 0, 0);
        acc[1][n] = __builtin_amdgcn_mfma_f32_16x16x32_bf16(pa1, bv, acc[1][n], 0, 0, 0);
      }
    }
    __builtin_amdgcn_s_setprio(0);
  }
#undef STAGE_CHUNK
#pragma unroll
  for (int qt = 0; qt < 2; qt++)
#pragma unroll
    for (int r = 0; r < 4; r++) {
#pragma unroll
      for (int off = 8; off; off >>= 1) lrow[qt][r] += __shfl_xor(lrow[qt][r], off);
      lrow[qt][r] = 1.f / lrow[qt][r];
    }
#pragma unroll
  for (int qt = 0; qt < 2; qt++)
#pragma unroll
    for (int n = 0; n < 8; n++)
#pragma unroll
      for (int r = 0; r < 4; r++) {
        int irow = q0 + qt * 16 + quad * 4 + r;
        Y[(size_t)irow * 4096 + h * 128 + n * 16 + l16] = f2bf(acc[qt][n][r] * lrow[qt][r]);
      }
}

extern "C" void kernel_launch(void* const* d_in, const int* in_sizes, int n_in,
                              void* d_out, int out_size, void* d_ws, size_t ws_size,
                              hipStream_t stream) {
  (void)in_sizes; (void)n_in; (void)out_size; (void)ws_size;
  const float* x     = (const float*)d_in[0];
  const float* cosb  = (const float*)d_in[1];
  const float* sinb  = (const float*)d_in[2];
  const float* Wqkv  = (const float*)d_in[3];
  const float* wq    = (const float*)d_in[4];
  const float* wk    = (const float*)d_in[5];
  const float* Wproj = (const float*)d_in[6];
  float* out = (float*)d_out;

  char* ws = (char*)d_ws;
  unsigned short* x_bf     = (unsigned short*)(ws);                 // 16 MB
  unsigned short* wqkv_bf  = (unsigned short*)(ws + 16777216);      // 48 MB
  unsigned short* wproj_bf = (unsigned short*)(ws + 67108864);      // 32 MB
  unsigned short* qkv      = (unsigned short*)(ws + 100663296);     // 24 MB (bf16)
  unsigned short* qr       = (unsigned short*)(ws + 150994944);     // 16 MB
  unsigned short* kr       = (unsigned short*)(ws + 167772160);     // 4 MB
  unsigned short* vt       = (unsigned short*)(ws + 171966464);     // 4 MB
  unsigned short* y        = (unsigned short*)(ws + 176160768);     // 16 MB

  cvt_all<<<49152, 256, 0, stream>>>(x, Wqkv, Wproj, x_bf, wqkv_bf, wproj_bf);
  gemm256<<<dim3(32, 8), 512, 0, stream>>>(x_bf, wqkv_bf, qkv, 2048, 6144, 4096);
  normrope<<<2048, 256, 0, stream>>>(qkv, cosb, sinb, wq, wk, qr, kr, vt);
  attn<<<dim3(32, 8), 512, 0, stream>>>(qr, kr, vt, y);
  gemm256p<<<dim3(16, 16), 512, 0, stream>>>(y, wproj_bf, out, 2048, 4096, 4096);
}